// Round 4
// baseline (881.374 us; speedup 1.0000x reference)
//
#include <hip/hip_runtime.h>
#include <hip/hip_bf16.h>

#define NND 50000
#define NCATS 3
#define VOC 1000
#define EDIM 16
#define NNUMF 16
#define FMAP 32
#define FIN 128          // 3*16 + 16 + 64
#define HID 64
#define NH 4
#define EB 400000
#define ETOT 450000      // EB + NND self loops
#define M1 256
#define M2 128
#define EPS_BN 1e-5f

__device__ __forceinline__ float lrelu(float x) { return x > 0.f ? x : 0.2f * x; }

// ================= CSR build (once; graph identical for both layers) =================
__global__ void k_zero_deg(int* __restrict__ deg) {
    int i = blockIdx.x * blockDim.x + threadIdx.x;
    if (i < NND) deg[i] = 0;
}

__global__ void k_count(const int* __restrict__ ei, int* __restrict__ deg) {
    int e = blockIdx.x * blockDim.x + threadIdx.x;
    if (e >= ETOT) return;
    int d = (e < EB) ? ei[EB + e] : e - EB;
    atomicAdd(&deg[d], 1);
}

__global__ __launch_bounds__(1024) void k_scan(const int* __restrict__ deg,
                                               int* __restrict__ off, int* __restrict__ cur) {
    __shared__ int part[1024];
    const int t = threadIdx.x;
    const int CH = (NND + 1023) / 1024;   // 49
    const int base = t * CH;
    int s = 0;
    for (int j = 0; j < CH; ++j) { int i = base + j; if (i < NND) s += deg[i]; }
    part[t] = s;
    __syncthreads();
    for (int ofs = 1; ofs < 1024; ofs <<= 1) {
        int v = (t >= ofs) ? part[t - ofs] : 0;
        __syncthreads();
        part[t] += v;
        __syncthreads();
    }
    int run = part[t] - s;    // exclusive prefix of this chunk
    for (int j = 0; j < CH; ++j) {
        int i = base + j;
        if (i < NND) { off[i] = run; cur[i] = run; run += deg[i]; }
    }
    if (t == 0) off[NND] = ETOT;
}

__global__ void k_fill(const int* __restrict__ ei, int* __restrict__ cur,
                       int* __restrict__ srcs) {
    int e = blockIdx.x * blockDim.x + threadIdx.x;
    if (e >= ETOT) return;
    int s, d;
    if (e < EB) { s = ei[e]; d = ei[EB + e]; } else { s = d = e - EB; }
    int p = atomicAdd(&cur[d], 1);
    srcs[p] = s;
}

// ================= K1: featurize + project (128 -> 64), 16-node tiles =================
__global__ __launch_bounds__(256) void k_feat_proj(
    const int* __restrict__ x_cat, const float* __restrict__ x_num,
    const float* __restrict__ x_coord, const float* __restrict__ emb,
    const float* __restrict__ fB, const float* __restrict__ pW,
    const float* __restrict__ pb, float* __restrict__ xout)
{
    __shared__ float Wl[FIN * HID];   // 32 KB
    __shared__ float feat[16][FIN];   // 8 KB
    const int tid = threadIdx.x;
    for (int i = tid; i < FIN * HID; i += 256) Wl[i] = pW[i];
    const int wid = tid >> 6, lane = tid & 63;
    const int col = lane, ng = wid;
    const float bias = pb[col];
    const int ntiles = NND / 16;
    for (int t = blockIdx.x; t < ntiles; t += gridDim.x) {
        const int n0 = t * 16;
        __syncthreads();
        #pragma unroll
        for (int r = 0; r < 4; ++r) {
            const int nn = wid * 4 + r;
            const int n = n0 + nn;
            float v;
            if (lane < 48) {
                int c = lane >> 4, j = lane & 15;
                int idx = x_cat[n * NCATS + c];
                v = emb[((size_t)c * VOC + idx) * EDIM + j];
            } else {
                v = x_num[n * NNUMF + (lane - 48)];
            }
            feat[nn][lane] = v;
            float c0 = x_coord[n * 2 + 0], c1 = x_coord[n * 2 + 1];
            int f = lane & 31;
            float xp = 6.283185307179586f * (c0 * fB[f] + c1 * fB[FMAP + f]);
            feat[nn][64 + lane] = (lane < 32) ? sinf(xp) : cosf(xp);
        }
        __syncthreads();
        float acc[4] = {bias, bias, bias, bias};
        #pragma unroll 4
        for (int k = 0; k < FIN; ++k) {
            float w = Wl[k * HID + col];
            #pragma unroll
            for (int j = 0; j < 4; ++j)
                acc[j] = fmaf(feat[ng + 4 * j][k], w, acc[j]);
        }
        #pragma unroll
        for (int j = 0; j < 4; ++j)
            xout[(size_t)(n0 + ng + 4 * j) * HID + col] = acc[j];
    }
}

// ================= K2a: va = W @ att (64x8) + zero bnst =================
__global__ __launch_bounds__(512) void k_va(
    const float* __restrict__ W, const float* __restrict__ aS,
    const float* __restrict__ aD, float* __restrict__ va, float* __restrict__ bnst)
{
    const int t = threadIdx.x;
    const int k = t >> 3, q = t & 7, hh = q & 3;
    const float* a = (q >= 4) ? aD : aS;
    float s = 0.f;
    #pragma unroll 8
    for (int d = 0; d < HID; ++d)
        s += W[k * 256 + hh * 64 + d] * a[hh * 64 + d];
    va[k * 8 + q] = s;
    if (t < 128) bnst[t] = 0.f;
}

// ================= K2b: alphas from x =================
__global__ __launch_bounds__(256) void k_alpha2(
    const float* __restrict__ x, const float* __restrict__ va,
    float* __restrict__ alphS, float* __restrict__ alphD)
{
    __shared__ float vas[64 * 8];
    const int tid = threadIdx.x;
    for (int i = tid; i < 512; i += 256) vas[i] = va[i];
    __syncthreads();
    const int lane = tid & 63, wid = tid >> 6;
    const float4 vS = *(const float4*)&vas[lane * 8];
    const float4 vD = *(const float4*)&vas[lane * 8 + 4];
    for (int n = blockIdx.x * 4 + wid; n < NND; n += gridDim.x * 4) {
        float v = x[(size_t)n * HID + lane];
        float s0 = v * vS.x, s1 = v * vS.y, s2 = v * vS.z, s3 = v * vS.w;
        float d0 = v * vD.x, d1 = v * vD.y, d2 = v * vD.z, d3 = v * vD.w;
        #pragma unroll
        for (int ofs = 32; ofs; ofs >>= 1) {
            s0 += __shfl_xor(s0, ofs, 64); s1 += __shfl_xor(s1, ofs, 64);
            s2 += __shfl_xor(s2, ofs, 64); s3 += __shfl_xor(s3, ofs, 64);
            d0 += __shfl_xor(d0, ofs, 64); d1 += __shfl_xor(d1, ofs, 64);
            d2 += __shfl_xor(d2, ofs, 64); d3 += __shfl_xor(d3, ofs, 64);
        }
        if (lane == 0) {
            *(float4*)(alphS + (size_t)n * 4) = make_float4(s0, s1, s2, s3);
            *(float4*)(alphD + (size_t)n * 4) = make_float4(d0, d1, d2, d3);
        }
    }
}

// ====== K3: aggregate x into per-head y (attention is linear: y_h = sum a_j^h x[s_j]) ======
__global__ __launch_bounds__(256) void k_aggregate_y(
    const int* __restrict__ off, const int* __restrict__ srcs,
    const float* __restrict__ alphS, const float* __restrict__ alphD,
    const float* __restrict__ x, float* __restrict__ y)
{
    const int lane = threadIdx.x & 63;
    int gw = blockIdx.x * 4 + (threadIdx.x >> 6);
    const int nw = gridDim.x * 4;
    for (int d = gw; d < NND; d += nw) {
        const int o0 = off[d], o1 = off[d + 1];
        const int deg = o1 - o0;
        const float4 ad = *(const float4*)(alphD + (size_t)d * 4);
        // pass 1: denominators; lanes keep first-chunk (sE, weights) in regs
        float dn0 = 0.f, dn1 = 0.f, dn2 = 0.f, dn3 = 0.f;
        int sE = 0; float w0 = 0.f, w1 = 0.f, w2 = 0.f, w3 = 0.f;
        for (int i = lane; i < deg; i += 64) {
            int s = srcs[o0 + i];
            float4 as = *(const float4*)(alphS + (size_t)s * 4);
            float e0 = __expf(lrelu(as.x + ad.x));
            float e1 = __expf(lrelu(as.y + ad.y));
            float e2 = __expf(lrelu(as.z + ad.z));
            float e3 = __expf(lrelu(as.w + ad.w));
            dn0 += e0; dn1 += e1; dn2 += e2; dn3 += e3;
            if (i < 64) { sE = s; w0 = e0; w1 = e1; w2 = e2; w3 = e3; }
        }
        #pragma unroll
        for (int ofs = 32; ofs; ofs >>= 1) {
            dn0 += __shfl_xor(dn0, ofs, 64); dn1 += __shfl_xor(dn1, ofs, 64);
            dn2 += __shfl_xor(dn2, ofs, 64); dn3 += __shfl_xor(dn3, ofs, 64);
        }
        const float i0 = __fdividef(1.f, dn0 + 1e-16f);
        const float i1 = __fdividef(1.f, dn1 + 1e-16f);
        const float i2 = __fdividef(1.f, dn2 + 1e-16f);
        const float i3 = __fdividef(1.f, dn3 + 1e-16f);
        float y0 = 0.f, y1 = 0.f, y2 = 0.f, y3 = 0.f;   // lane = x-dim k
        for (int c0 = 0; c0 < deg; c0 += 64) {
            const int m = min(64, deg - c0);
            if (c0 > 0) {
                sE = 0; w0 = w1 = w2 = w3 = 0.f;
                if (lane < m) {
                    sE = srcs[o0 + c0 + lane];
                    float4 as = *(const float4*)(alphS + (size_t)sE * 4);
                    w0 = __expf(lrelu(as.x + ad.x));
                    w1 = __expf(lrelu(as.y + ad.y));
                    w2 = __expf(lrelu(as.z + ad.z));
                    w3 = __expf(lrelu(as.w + ad.w));
                }
            }
            for (int j = 0; j < m; ++j) {
                const int   sj = __shfl(sE, j, 64);
                const float a0 = __shfl(w0, j, 64), a1 = __shfl(w1, j, 64);
                const float a2 = __shfl(w2, j, 64), a3 = __shfl(w3, j, 64);
                const float xv = x[(size_t)sj * HID + lane];
                y0 = fmaf(a0, xv, y0); y1 = fmaf(a1, xv, y1);
                y2 = fmaf(a2, xv, y2); y3 = fmaf(a3, xv, y3);
            }
        }
        float* yd = y + (size_t)d * 256;
        yd[lane]       = y0 * i0;
        yd[64 + lane]  = y1 * i1;
        yd[128 + lane] = y2 * i2;
        yd[192 + lane] = y3 * i3;
    }
}

// ====== K4: out = 0.25 * (y @ Ws) + b  (Ws = head-stacked gatW), + BN stats ======
__global__ __launch_bounds__(256, 1) void k_transform(
    const float* __restrict__ y, const float* __restrict__ W,
    const float* __restrict__ gat_b, float* __restrict__ accum,
    float* __restrict__ bnst)
{
    __shared__ float Ws[256 * 64];    // 64 KB: Ws[r][c] = W[k][h*64+c], r = h*64+k
    __shared__ float ys[16 * 256];    // 16 KB
    __shared__ float part[4 * 16 * 64]; // 16 KB
    const int tid = threadIdx.x;
    for (int i = tid; i < 256 * 64; i += 256) {
        int r = i >> 6, c = i & 63;
        Ws[i] = W[(r & 63) * 256 + (r >> 6) * 64 + c];
    }
    const int col = tid & 63;
    const int ks = (tid >> 6) * 64;   // K-slice per wave (no redundant LDS reads)
    const float bd = gat_b[col];
    float s1 = 0.f, s2 = 0.f;
    const int ntiles = NND / 16;
    for (int t = blockIdx.x; t < ntiles; t += gridDim.x) {
        const int n0 = t * 16;
        __syncthreads();
        {
            const float4* src = (const float4*)(y + (size_t)n0 * 256);
            float4* dst = (float4*)ys;
            #pragma unroll
            for (int q = 0; q < 4; ++q) dst[tid + q * 256] = src[tid + q * 256];
        }
        __syncthreads();
        float acc[16];
        #pragma unroll
        for (int n = 0; n < 16; ++n) acc[n] = 0.f;
        for (int kk = ks; kk < ks + 64; kk += 4) {
            float wv0 = Ws[(kk + 0) * 64 + col];
            float wv1 = Ws[(kk + 1) * 64 + col];
            float wv2 = Ws[(kk + 2) * 64 + col];
            float wv3 = Ws[(kk + 3) * 64 + col];
            #pragma unroll
            for (int n = 0; n < 16; ++n) {
                float4 yv = *(const float4*)&ys[n * 256 + kk];
                acc[n] = fmaf(yv.x, wv0, fmaf(yv.y, wv1, fmaf(yv.z, wv2, fmaf(yv.w, wv3, acc[n]))));
            }
        }
        #pragma unroll
        for (int n = 0; n < 16; ++n)
            part[ks * 16 + n * 64 + col] = acc[n];   // ks*16 == (tid>>6)*1024
        __syncthreads();
        const int ng = tid >> 6;
        #pragma unroll
        for (int i2 = 0; i2 < 4; ++i2) {
            int n = ng * 4 + i2;
            float g = part[n * 64 + col] + part[1024 + n * 64 + col]
                    + part[2048 + n * 64 + col] + part[3072 + n * 64 + col];
            g = g * 0.25f + bd;
            accum[(size_t)(n0 + n) * HID + col] = g;
            s1 += g; s2 += g * g;
        }
    }
    __syncthreads();
    part[tid] = s1; part[256 + tid] = s2;
    __syncthreads();
    if (tid < 64) {
        float a = part[tid] + part[tid + 64] + part[tid + 128] + part[tid + 192];
        float b = part[256 + tid] + part[256 + tid + 64] + part[256 + tid + 128]
                + part[256 + tid + 192];
        atomicAdd(&bnst[tid], a);
        atomicAdd(&bnst[64 + tid], b);
    }
}

// ================= K5: BN apply + relu + residual (float4, in place on x) =================
__global__ void k_bn_apply(const float* __restrict__ accum, const float* __restrict__ bnst,
                           const float* __restrict__ gamma, const float* __restrict__ beta,
                           float* __restrict__ x)
{
    int i = blockIdx.x * blockDim.x + threadIdx.x;   // float4 index
    if (i >= NND * 16) return;
    int dg = (i & 15) * 4;
    float4 a = ((const float4*)accum)[i];
    float4 xv = ((float4*)x)[i];
    float r[4]; float av[4] = {a.x, a.y, a.z, a.w}; float xx[4] = {xv.x, xv.y, xv.z, xv.w};
    #pragma unroll
    for (int c = 0; c < 4; ++c) {
        int d = dg + c;
        float mu = bnst[d] * (1.f / NND);
        float var = bnst[64 + d] * (1.f / NND) - mu * mu;
        float inv = rsqrtf(var + EPS_BN);
        float yv = (av[c] - mu) * inv * gamma[d] + beta[d];
        r[c] = fmaxf(yv, 0.f) + xx[c];
    }
    ((float4*)x)[i] = make_float4(r[0], r[1], r[2], r[3]);
}

// ====== K6: fused MLP: z1 = relu(x@W1+b1); z2 = relu(z1@W2+b2); out = z2@W3+b3 ======
__global__ __launch_bounds__(256, 1) void k_mlp_fused(
    const float* __restrict__ x, const float* __restrict__ W1, const float* __restrict__ b1,
    const float* __restrict__ W2, const float* __restrict__ b2,
    const float* __restrict__ W3, const float* __restrict__ b3, float* __restrict__ out)
{
    __shared__ float W2s[256 * 128];  // 128 KB, resident
    __shared__ float xs[16][64];      // 4 KB
    __shared__ float z1s[16][256];    // 16 KB
    __shared__ float w3s[128];
    const int tid = threadIdx.x;
    {
        const float4* src = (const float4*)W2;
        float4* dst = (float4*)W2s;
        for (int i = tid; i < 8192; i += 256) dst[i] = src[i];
    }
    if (tid < 128) w3s[tid] = W3[tid];
    float w1r[64];                    // W1 column `tid` in registers
    #pragma unroll
    for (int k = 0; k < 64; ++k) w1r[k] = W1[k * 256 + tid];
    const float b1r = b1[tid];
    const int tj = tid & 31, tn = tid >> 5;   // z2: 4 cols x 2 nodes per thread
    float bias2[4];
    #pragma unroll
    for (int q = 0; q < 4; ++q) bias2[q] = b2[tj * 4 + q];
    const float bb3 = b3[0];
    const int ntiles = NND / 16;
    for (int t = blockIdx.x; t < ntiles; t += gridDim.x) {
        const int n0 = t * 16;
        __syncthreads();
        ((float4*)xs)[tid] = ((const float4*)(x + (size_t)n0 * 64))[tid];
        __syncthreads();
        // --- z1: col = tid, 16 nodes ---
        float acc1[16];
        #pragma unroll
        for (int n = 0; n < 16; ++n) acc1[n] = b1r;
        #pragma unroll
        for (int kk = 0; kk < 64; kk += 4) {
            #pragma unroll
            for (int n = 0; n < 16; ++n) {
                float4 xv = *(const float4*)&xs[n][kk];
                acc1[n] = fmaf(xv.x, w1r[kk], fmaf(xv.y, w1r[kk + 1],
                          fmaf(xv.z, w1r[kk + 2], fmaf(xv.w, w1r[kk + 3], acc1[n]))));
            }
        }
        #pragma unroll
        for (int n = 0; n < 16; ++n) z1s[n][tid] = fmaxf(acc1[n], 0.f);
        __syncthreads();
        // --- z2 + out ---
        float acc2[2][4];
        #pragma unroll
        for (int i2 = 0; i2 < 2; ++i2)
            #pragma unroll
            for (int q = 0; q < 4; ++q) acc2[i2][q] = bias2[q];
        #pragma unroll 4
        for (int kk = 0; kk < 256; kk += 4) {
            float4 wv0 = *(const float4*)&W2s[(kk + 0) * 128 + tj * 4];
            float4 wv1 = *(const float4*)&W2s[(kk + 1) * 128 + tj * 4];
            float4 wv2 = *(const float4*)&W2s[(kk + 2) * 128 + tj * 4];
            float4 wv3 = *(const float4*)&W2s[(kk + 3) * 128 + tj * 4];
            #pragma unroll
            for (int i2 = 0; i2 < 2; ++i2) {
                float4 zv = *(const float4*)&z1s[tn * 2 + i2][kk];
                acc2[i2][0] = fmaf(zv.x, wv0.x, acc2[i2][0]);
                acc2[i2][1] = fmaf(zv.x, wv0.y, acc2[i2][1]);
                acc2[i2][2] = fmaf(zv.x, wv0.z, acc2[i2][2]);
                acc2[i2][3] = fmaf(zv.x, wv0.w, acc2[i2][3]);
                acc2[i2][0] = fmaf(zv.y, wv1.x, acc2[i2][0]);
                acc2[i2][1] = fmaf(zv.y, wv1.y, acc2[i2][1]);
                acc2[i2][2] = fmaf(zv.y, wv1.z, acc2[i2][2]);
                acc2[i2][3] = fmaf(zv.y, wv1.w, acc2[i2][3]);
                acc2[i2][0] = fmaf(zv.z, wv2.x, acc2[i2][0]);
                acc2[i2][1] = fmaf(zv.z, wv2.y, acc2[i2][1]);
                acc2[i2][2] = fmaf(zv.z, wv2.z, acc2[i2][2]);
                acc2[i2][3] = fmaf(zv.z, wv2.w, acc2[i2][3]);
                acc2[i2][0] = fmaf(zv.w, wv3.x, acc2[i2][0]);
                acc2[i2][1] = fmaf(zv.w, wv3.y, acc2[i2][1]);
                acc2[i2][2] = fmaf(zv.w, wv3.z, acc2[i2][2]);
                acc2[i2][3] = fmaf(zv.w, wv3.w, acc2[i2][3]);
            }
        }
        float p[2];
        #pragma unroll
        for (int i2 = 0; i2 < 2; ++i2) {
            p[i2] = fmaxf(acc2[i2][0], 0.f) * w3s[tj * 4 + 0]
                  + fmaxf(acc2[i2][1], 0.f) * w3s[tj * 4 + 1]
                  + fmaxf(acc2[i2][2], 0.f) * w3s[tj * 4 + 2]
                  + fmaxf(acc2[i2][3], 0.f) * w3s[tj * 4 + 3];
        }
        #pragma unroll
        for (int ofs = 16; ofs; ofs >>= 1) {
            p[0] += __shfl_xor(p[0], ofs, 64);
            p[1] += __shfl_xor(p[1], ofs, 64);
        }
        if (tj == 0) {
            out[n0 + tn * 2 + 0] = p[0] + bb3;
            out[n0 + tn * 2 + 1] = p[1] + bb3;
        }
    }
}

extern "C" void kernel_launch(void* const* d_in, const int* in_sizes, int n_in,
                              void* d_out, int out_size, void* d_ws, size_t ws_size,
                              hipStream_t stream) {
    const int*   x_cat   = (const int*)  d_in[0];
    const float* x_num   = (const float*)d_in[1];
    const float* x_coord = (const float*)d_in[2];
    const int*   eidx    = (const int*)  d_in[3];
    const float* emb     = (const float*)d_in[4];
    const float* fB      = (const float*)d_in[5];
    const float* pW      = (const float*)d_in[6];
    const float* pb      = (const float*)d_in[7];
    const float* gatW    = (const float*)d_in[8];
    const float* attS    = (const float*)d_in[9];
    const float* attD    = (const float*)d_in[10];
    const float* gatB    = (const float*)d_in[11];
    const float* bnG     = (const float*)d_in[12];
    const float* bnB     = (const float*)d_in[13];
    const float* W1      = (const float*)d_in[14];
    const float* b1      = (const float*)d_in[15];
    const float* W2      = (const float*)d_in[16];
    const float* b2      = (const float*)d_in[17];
    const float* W3      = (const float*)d_in[18];
    const float* b3      = (const float*)d_in[19];
    float* out = (float*)d_out;

    char* p = (char*)d_ws;
    float* x     = (float*)p;  p += (size_t)NND * HID * 4;
    float* y     = (float*)p;  p += (size_t)NND * 256 * 4;
    float* alphS = (float*)p;  p += (size_t)NND * NH * 4;
    float* alphD = (float*)p;  p += (size_t)NND * NH * 4;
    float* accum = (float*)p;  p += (size_t)NND * HID * 4;
    float* bnst  = (float*)p;  p += 512;
    float* va    = (float*)p;  p += 512 * 4;
    int*   deg   = (int*)p;    p += (size_t)NND * 4;
    int*   cur   = (int*)p;    p += (size_t)NND * 4;
    int*   off   = (int*)p;    p += (size_t)(NND + 1) * 4 + 4;
    int*   srcs  = (int*)p;    p += (size_t)ETOT * 4;

    // CSR build (graph constant across layers)
    k_zero_deg<<<(NND + 255) / 256, 256, 0, stream>>>(deg);
    k_count<<<(ETOT + 255) / 256, 256, 0, stream>>>(eidx, deg);
    k_scan<<<1, 1024, 0, stream>>>(deg, off, cur);
    k_fill<<<(ETOT + 255) / 256, 256, 0, stream>>>(eidx, cur, srcs);

    k_feat_proj<<<512, 256, 0, stream>>>(x_cat, x_num, x_coord, emb, fB, pW, pb, x);
    for (int l = 0; l < 2; ++l) {
        k_va<<<1, 512, 0, stream>>>(gatW + (size_t)l * HID * 256,
                                    attS + l * NH * HID, attD + l * NH * HID, va, bnst);
        k_alpha2<<<2048, 256, 0, stream>>>(x, va, alphS, alphD);
        k_aggregate_y<<<1024, 256, 0, stream>>>(off, srcs, alphS, alphD, x, y);
        k_transform<<<625, 256, 0, stream>>>(y, gatW + (size_t)l * HID * 256,
                                             gatB + l * HID, accum, bnst);
        k_bn_apply<<<3125, 256, 0, stream>>>(accum, bnst, bnG + l * HID, bnB + l * HID, x);
    }
    k_mlp_fused<<<625, 256, 0, stream>>>(x, W1, b1, W2, b2, W3, b3, out);
}

// Round 5
// 633.219 us; speedup vs baseline: 1.3919x; 1.3919x over previous
//
#include <hip/hip_runtime.h>
#include <hip/hip_bf16.h>

#define NND 50000
#define NCATS 3
#define VOC 1000
#define EDIM 16
#define NNUMF 16
#define FMAP 32
#define FIN 128          // 3*16 + 16 + 64
#define HID 64
#define NH 4
#define EB 400000
#define ETOT 450000      // EB + NND self loops
#define M1 256
#define M2 128
#define EPS_BN 1e-5f

typedef __attribute__((ext_vector_type(8))) short bf16x8;
typedef __attribute__((ext_vector_type(4))) float f32x4;

__device__ __forceinline__ float lrelu(float x) { return x > 0.f ? x : 0.2f * x; }

__device__ __forceinline__ unsigned short bfu(float f) {
    unsigned u = __float_as_uint(f);
    unsigned r = (u + 0x7FFFu + ((u >> 16) & 1u)) >> 16;
    return (unsigned short)r;
}

// ================= CSR build (once; graph identical for both layers) =================
__global__ void k_zero_deg(int* __restrict__ deg) {
    int i = blockIdx.x * blockDim.x + threadIdx.x;
    if (i < NND) deg[i] = 0;
}

__global__ void k_count(const int* __restrict__ ei, int* __restrict__ deg) {
    int e = blockIdx.x * blockDim.x + threadIdx.x;
    if (e >= ETOT) return;
    int d = (e < EB) ? ei[EB + e] : e - EB;
    atomicAdd(&deg[d], 1);
}

__global__ __launch_bounds__(1024) void k_scan(const int* __restrict__ deg,
                                               int* __restrict__ off, int* __restrict__ cur) {
    __shared__ int part[1024];
    const int t = threadIdx.x;
    const int CH = (NND + 1023) / 1024;   // 49
    const int base = t * CH;
    int s = 0;
    for (int j = 0; j < CH; ++j) { int i = base + j; if (i < NND) s += deg[i]; }
    part[t] = s;
    __syncthreads();
    for (int ofs = 1; ofs < 1024; ofs <<= 1) {
        int v = (t >= ofs) ? part[t - ofs] : 0;
        __syncthreads();
        part[t] += v;
        __syncthreads();
    }
    int run = part[t] - s;    // exclusive prefix of this chunk
    for (int j = 0; j < CH; ++j) {
        int i = base + j;
        if (i < NND) { off[i] = run; cur[i] = run; run += deg[i]; }
    }
    if (t == 0) off[NND] = ETOT;
}

__global__ void k_fill(const int* __restrict__ ei, int* __restrict__ cur,
                       int* __restrict__ srcs) {
    int e = blockIdx.x * blockDim.x + threadIdx.x;
    if (e >= ETOT) return;
    int s, d;
    if (e < EB) { s = ei[e]; d = ei[EB + e]; } else { s = d = e - EB; }
    int p = atomicAdd(&cur[d], 1);
    srcs[p] = s;
}

// ============== pack W1/W2 into bf16 MFMA B-fragment order ==============
// frag idx layout: value at ((cb*KCH + kc)*64 + lane)*8 + j  equals
//   W[k][c] with k = kc*32 + (lane>>4)*8 + j, c = cb*16 + (lane&15)
__global__ __launch_bounds__(256) void k_packw(
    const float* __restrict__ W1, const float* __restrict__ W2,
    unsigned short* __restrict__ W1f, unsigned short* __restrict__ W2f)
{
    int i = blockIdx.x * 256 + threadIdx.x;   // grid covers 49152
    if (i < 16384) {   // W1: 16 col-blocks x 2 k-chunks
        int j = i & 7, l = (i >> 3) & 63, t = i >> 9;
        int kc = t & 1, cb = t >> 1;
        int k = kc * 32 + ((l >> 4) * 8) + j, c = cb * 16 + (l & 15);
        W1f[i] = bfu(W1[k * 256 + c]);
    }
    if (i < 32768) {   // W2: 8 col-blocks x 8 k-chunks
        int j = i & 7, l = (i >> 3) & 63, t = i >> 9;
        int kc = t & 7, cb = t >> 3;
        int k = kc * 32 + ((l >> 4) * 8) + j, c = cb * 16 + (l & 15);
        W2f[i] = bfu(W2[k * 128 + c]);
    }
}

// ================= K1: featurize + project (128 -> 64), 16-node tiles =================
__global__ __launch_bounds__(256) void k_feat_proj(
    const int* __restrict__ x_cat, const float* __restrict__ x_num,
    const float* __restrict__ x_coord, const float* __restrict__ emb,
    const float* __restrict__ fB, const float* __restrict__ pW,
    const float* __restrict__ pb, float* __restrict__ xout)
{
    __shared__ float Wl[FIN * HID];   // 32 KB
    __shared__ float feat[16][FIN];   // 8 KB
    const int tid = threadIdx.x;
    for (int i = tid; i < FIN * HID; i += 256) Wl[i] = pW[i];
    const int wid = tid >> 6, lane = tid & 63;
    const int col = lane, ng = wid;
    const float bias = pb[col];
    const int ntiles = NND / 16;
    for (int t = blockIdx.x; t < ntiles; t += gridDim.x) {
        const int n0 = t * 16;
        __syncthreads();
        #pragma unroll
        for (int r = 0; r < 4; ++r) {
            const int nn = wid * 4 + r;
            const int n = n0 + nn;
            float v;
            if (lane < 48) {
                int c = lane >> 4, j = lane & 15;
                int idx = x_cat[n * NCATS + c];
                v = emb[((size_t)c * VOC + idx) * EDIM + j];
            } else {
                v = x_num[n * NNUMF + (lane - 48)];
            }
            feat[nn][lane] = v;
            float c0 = x_coord[n * 2 + 0], c1 = x_coord[n * 2 + 1];
            int f = lane & 31;
            float xp = 6.283185307179586f * (c0 * fB[f] + c1 * fB[FMAP + f]);
            feat[nn][64 + lane] = (lane < 32) ? sinf(xp) : cosf(xp);
        }
        __syncthreads();
        float acc[4] = {bias, bias, bias, bias};
        #pragma unroll 4
        for (int k = 0; k < FIN; ++k) {
            float w = Wl[k * HID + col];
            #pragma unroll
            for (int j = 0; j < 4; ++j)
                acc[j] = fmaf(feat[ng + 4 * j][k], w, acc[j]);
        }
        #pragma unroll
        for (int j = 0; j < 4; ++j)
            xout[(size_t)(n0 + ng + 4 * j) * HID + col] = acc[j];
    }
}

// ================= K2a: va = W @ att (64x8) + zero bnst =================
__global__ __launch_bounds__(512) void k_va(
    const float* __restrict__ W, const float* __restrict__ aS,
    const float* __restrict__ aD, float* __restrict__ va, float* __restrict__ bnst)
{
    const int t = threadIdx.x;
    const int k = t >> 3, q = t & 7, hh = q & 3;
    const float* a = (q >= 4) ? aD : aS;
    float s = 0.f;
    #pragma unroll 8
    for (int d = 0; d < HID; ++d)
        s += W[k * 256 + hh * 64 + d] * a[hh * 64 + d];
    va[k * 8 + q] = s;
    if (t < 128) bnst[t] = 0.f;
}

// ================= K2b: alphas from x =================
__global__ __launch_bounds__(256) void k_alpha2(
    const float* __restrict__ x, const float* __restrict__ va,
    float* __restrict__ alphS, float* __restrict__ alphD)
{
    __shared__ float vas[64 * 8];
    const int tid = threadIdx.x;
    for (int i = tid; i < 512; i += 256) vas[i] = va[i];
    __syncthreads();
    const int lane = tid & 63, wid = tid >> 6;
    const float4 vS = *(const float4*)&vas[lane * 8];
    const float4 vD = *(const float4*)&vas[lane * 8 + 4];
    for (int n = blockIdx.x * 4 + wid; n < NND; n += gridDim.x * 4) {
        float v = x[(size_t)n * HID + lane];
        float s0 = v * vS.x, s1 = v * vS.y, s2 = v * vS.z, s3 = v * vS.w;
        float d0 = v * vD.x, d1 = v * vD.y, d2 = v * vD.z, d3 = v * vD.w;
        #pragma unroll
        for (int ofs = 32; ofs; ofs >>= 1) {
            s0 += __shfl_xor(s0, ofs, 64); s1 += __shfl_xor(s1, ofs, 64);
            s2 += __shfl_xor(s2, ofs, 64); s3 += __shfl_xor(s3, ofs, 64);
            d0 += __shfl_xor(d0, ofs, 64); d1 += __shfl_xor(d1, ofs, 64);
            d2 += __shfl_xor(d2, ofs, 64); d3 += __shfl_xor(d3, ofs, 64);
        }
        if (lane == 0) {
            *(float4*)(alphS + (size_t)n * 4) = make_float4(s0, s1, s2, s3);
            *(float4*)(alphD + (size_t)n * 4) = make_float4(d0, d1, d2, d3);
        }
    }
}

// ====== K3: aggregate x into per-head y (attention is linear) — 4-deep pipelined ======
__global__ __launch_bounds__(256) void k_aggregate_y(
    const int* __restrict__ off, const int* __restrict__ srcs,
    const float* __restrict__ alphS, const float* __restrict__ alphD,
    const float* __restrict__ x, float* __restrict__ y)
{
    const int lane = threadIdx.x & 63;
    int gw = blockIdx.x * 4 + (threadIdx.x >> 6);
    const int nw = gridDim.x * 4;
    for (int d = gw; d < NND; d += nw) {
        const int o0 = off[d], o1 = off[d + 1];
        const int deg = o1 - o0;
        const float4 ad = *(const float4*)(alphD + (size_t)d * 4);
        float dn0 = 0.f, dn1 = 0.f, dn2 = 0.f, dn3 = 0.f;
        int sE = 0; float w0 = 0.f, w1 = 0.f, w2 = 0.f, w3 = 0.f;
        for (int i = lane; i < deg; i += 64) {
            int s = srcs[o0 + i];
            float4 as = *(const float4*)(alphS + (size_t)s * 4);
            float e0 = __expf(lrelu(as.x + ad.x));
            float e1 = __expf(lrelu(as.y + ad.y));
            float e2 = __expf(lrelu(as.z + ad.z));
            float e3 = __expf(lrelu(as.w + ad.w));
            dn0 += e0; dn1 += e1; dn2 += e2; dn3 += e3;
            if (i < 64) { sE = s; w0 = e0; w1 = e1; w2 = e2; w3 = e3; }
        }
        #pragma unroll
        for (int ofs = 32; ofs; ofs >>= 1) {
            dn0 += __shfl_xor(dn0, ofs, 64); dn1 += __shfl_xor(dn1, ofs, 64);
            dn2 += __shfl_xor(dn2, ofs, 64); dn3 += __shfl_xor(dn3, ofs, 64);
        }
        const float i0 = __fdividef(1.f, dn0 + 1e-16f);
        const float i1 = __fdividef(1.f, dn1 + 1e-16f);
        const float i2 = __fdividef(1.f, dn2 + 1e-16f);
        const float i3 = __fdividef(1.f, dn3 + 1e-16f);
        float y0 = 0.f, y1 = 0.f, y2 = 0.f, y3 = 0.f;   // lane = x-dim k
        for (int c0 = 0; c0 < deg; c0 += 64) {
            const int m = min(64, deg - c0);
            if (c0 > 0) {
                sE = 0; w0 = w1 = w2 = w3 = 0.f;
                if (lane < m) {
                    sE = srcs[o0 + c0 + lane];
                    float4 as = *(const float4*)(alphS + (size_t)sE * 4);
                    w0 = __expf(lrelu(as.x + ad.x));
                    w1 = __expf(lrelu(as.y + ad.y));
                    w2 = __expf(lrelu(as.z + ad.z));
                    w3 = __expf(lrelu(as.w + ad.w));
                }
            }
            int j = 0;
            for (; j + 4 <= m; j += 4) {
                const int sj0 = __shfl(sE, j + 0, 64), sj1 = __shfl(sE, j + 1, 64);
                const int sj2 = __shfl(sE, j + 2, 64), sj3 = __shfl(sE, j + 3, 64);
                const float xv0 = x[(size_t)sj0 * HID + lane];
                const float xv1 = x[(size_t)sj1 * HID + lane];
                const float xv2 = x[(size_t)sj2 * HID + lane];
                const float xv3 = x[(size_t)sj3 * HID + lane];
                float a0, a1, a2, a3;
                a0 = __shfl(w0, j + 0, 64); a1 = __shfl(w1, j + 0, 64);
                a2 = __shfl(w2, j + 0, 64); a3 = __shfl(w3, j + 0, 64);
                y0 = fmaf(a0, xv0, y0); y1 = fmaf(a1, xv0, y1);
                y2 = fmaf(a2, xv0, y2); y3 = fmaf(a3, xv0, y3);
                a0 = __shfl(w0, j + 1, 64); a1 = __shfl(w1, j + 1, 64);
                a2 = __shfl(w2, j + 1, 64); a3 = __shfl(w3, j + 1, 64);
                y0 = fmaf(a0, xv1, y0); y1 = fmaf(a1, xv1, y1);
                y2 = fmaf(a2, xv1, y2); y3 = fmaf(a3, xv1, y3);
                a0 = __shfl(w0, j + 2, 64); a1 = __shfl(w1, j + 2, 64);
                a2 = __shfl(w2, j + 2, 64); a3 = __shfl(w3, j + 2, 64);
                y0 = fmaf(a0, xv2, y0); y1 = fmaf(a1, xv2, y1);
                y2 = fmaf(a2, xv2, y2); y3 = fmaf(a3, xv2, y3);
                a0 = __shfl(w0, j + 3, 64); a1 = __shfl(w1, j + 3, 64);
                a2 = __shfl(w2, j + 3, 64); a3 = __shfl(w3, j + 3, 64);
                y0 = fmaf(a0, xv3, y0); y1 = fmaf(a1, xv3, y1);
                y2 = fmaf(a2, xv3, y2); y3 = fmaf(a3, xv3, y3);
            }
            for (; j < m; ++j) {
                const int   sj = __shfl(sE, j, 64);
                const float a0 = __shfl(w0, j, 64), a1 = __shfl(w1, j, 64);
                const float a2 = __shfl(w2, j, 64), a3 = __shfl(w3, j, 64);
                const float xv = x[(size_t)sj * HID + lane];
                y0 = fmaf(a0, xv, y0); y1 = fmaf(a1, xv, y1);
                y2 = fmaf(a2, xv, y2); y3 = fmaf(a3, xv, y3);
            }
        }
        float* yd = y + (size_t)d * 256;
        yd[lane]       = y0 * i0;
        yd[64 + lane]  = y1 * i1;
        yd[128 + lane] = y2 * i2;
        yd[192 + lane] = y3 * i3;
    }
}

// ====== K4: out = 0.25 * (y @ Ws) + b  (Ws = head-stacked gatW), + BN stats ======
__global__ __launch_bounds__(256, 1) void k_transform(
    const float* __restrict__ y, const float* __restrict__ W,
    const float* __restrict__ gat_b, float* __restrict__ accum,
    float* __restrict__ bnst)
{
    __shared__ float Ws[256 * 64];    // 64 KB: Ws[r][c] = W[k][h*64+c], r = h*64+k
    __shared__ float ys[16 * 256];    // 16 KB
    __shared__ float part[4 * 16 * 64]; // 16 KB
    const int tid = threadIdx.x;
    for (int i = tid; i < 256 * 64; i += 256) {
        int r = i >> 6, c = i & 63;
        Ws[i] = W[(r & 63) * 256 + (r >> 6) * 64 + c];
    }
    const int col = tid & 63;
    const int ks = (tid >> 6) * 64;   // K-slice per wave
    const float bd = gat_b[col];
    float s1 = 0.f, s2 = 0.f;
    const int ntiles = NND / 16;
    for (int t = blockIdx.x; t < ntiles; t += gridDim.x) {
        const int n0 = t * 16;
        __syncthreads();
        {
            const float4* src = (const float4*)(y + (size_t)n0 * 256);
            float4* dst = (float4*)ys;
            #pragma unroll
            for (int q = 0; q < 4; ++q) dst[tid + q * 256] = src[tid + q * 256];
        }
        __syncthreads();
        float acc[16];
        #pragma unroll
        for (int n = 0; n < 16; ++n) acc[n] = 0.f;
        for (int kk = ks; kk < ks + 64; kk += 4) {
            float wv0 = Ws[(kk + 0) * 64 + col];
            float wv1 = Ws[(kk + 1) * 64 + col];
            float wv2 = Ws[(kk + 2) * 64 + col];
            float wv3 = Ws[(kk + 3) * 64 + col];
            #pragma unroll
            for (int n = 0; n < 16; ++n) {
                float4 yv = *(const float4*)&ys[n * 256 + kk];
                acc[n] = fmaf(yv.x, wv0, fmaf(yv.y, wv1, fmaf(yv.z, wv2, fmaf(yv.w, wv3, acc[n]))));
            }
        }
        #pragma unroll
        for (int n = 0; n < 16; ++n)
            part[ks * 16 + n * 64 + col] = acc[n];
        __syncthreads();
        const int ng = tid >> 6;
        #pragma unroll
        for (int i2 = 0; i2 < 4; ++i2) {
            int n = ng * 4 + i2;
            float g = part[n * 64 + col] + part[1024 + n * 64 + col]
                    + part[2048 + n * 64 + col] + part[3072 + n * 64 + col];
            g = g * 0.25f + bd;
            accum[(size_t)(n0 + n) * HID + col] = g;
            s1 += g; s2 += g * g;
        }
    }
    __syncthreads();
    part[tid] = s1; part[256 + tid] = s2;
    __syncthreads();
    if (tid < 64) {
        float a = part[tid] + part[tid + 64] + part[tid + 128] + part[tid + 192];
        float b = part[256 + tid] + part[256 + tid + 64] + part[256 + tid + 128]
                + part[256 + tid + 192];
        atomicAdd(&bnst[tid], a);
        atomicAdd(&bnst[64 + tid], b);
    }
}

// ================= K5: BN apply + relu + residual (float4, in place on x) =================
__global__ void k_bn_apply(const float* __restrict__ accum, const float* __restrict__ bnst,
                           const float* __restrict__ gamma, const float* __restrict__ beta,
                           float* __restrict__ x)
{
    int i = blockIdx.x * blockDim.x + threadIdx.x;   // float4 index
    if (i >= NND * 16) return;
    int dg = (i & 15) * 4;
    float4 a = ((const float4*)accum)[i];
    float4 xv = ((float4*)x)[i];
    float r[4]; float av[4] = {a.x, a.y, a.z, a.w}; float xx[4] = {xv.x, xv.y, xv.z, xv.w};
    #pragma unroll
    for (int c = 0; c < 4; ++c) {
        int d = dg + c;
        float mu = bnst[d] * (1.f / NND);
        float var = bnst[64 + d] * (1.f / NND) - mu * mu;
        float inv = rsqrtf(var + EPS_BN);
        float yv = (av[c] - mu) * inv * gamma[d] + beta[d];
        r[c] = fmaxf(yv, 0.f) + xx[c];
    }
    ((float4*)x)[i] = make_float4(r[0], r[1], r[2], r[3]);
}

// ====== K6: fused MFMA MLP: z1=relu(x@W1+b1); z2=relu(z1@W2+b2); out=z2@W3+b3 ======
__global__ __launch_bounds__(256, 1) void k_mlp_mfma(
    const float* __restrict__ x,
    const unsigned short* __restrict__ W1f, const unsigned short* __restrict__ W2f,
    const float* __restrict__ b1, const float* __restrict__ b2,
    const float* __restrict__ W3, const float* __restrict__ b3,
    float* __restrict__ out)
{
    __shared__ __align__(16) unsigned short W1s[16384];  // 32 KB (frag order)
    __shared__ __align__(16) unsigned short W2s[32768];  // 64 KB (frag order)
    __shared__ __align__(16) unsigned short xs[64 * 64]; // 8 KB  bf16 x tile
    __shared__ __align__(16) unsigned short z1s[64 * 256]; // 32 KB bf16 z1 tile
    __shared__ float b1s[256], b2s[128], w3s[128];
    const int tid = threadIdx.x;
    const int lane = tid & 63, wid = tid >> 6;
    {
        const uint4* s1 = (const uint4*)W1f; uint4* d1 = (uint4*)W1s;
        for (int i = tid; i < 2048; i += 256) d1[i] = s1[i];
        const uint4* s2 = (const uint4*)W2f; uint4* d2 = (uint4*)W2s;
        for (int i = tid; i < 4096; i += 256) d2[i] = s2[i];
        if (tid < 256) b1s[tid] = b1[tid];
        if (tid < 128) { b2s[tid] = b2[tid]; w3s[tid] = W3[tid]; }
    }
    const float bb3 = b3[0];
    const int nw = wid * 16;               // this wave's node offset in tile
    const int cl = lane & 15, lg = lane >> 4;
    const int ntiles = (NND + 63) / 64;    // 782
    for (int t = blockIdx.x; t < ntiles; t += gridDim.x) {
        const int n0 = t * 64;
        __syncthreads();
        // stage x tile -> bf16
        #pragma unroll
        for (int q = 0; q < 4; ++q) {
            int i = q * 256 + tid;          // 0..1023
            int row = i >> 4, k4 = (i & 15) * 4;
            int n = n0 + row;
            float4 v = (n < NND) ? *(const float4*)(x + (size_t)n * HID + k4)
                                 : make_float4(0.f, 0.f, 0.f, 0.f);
            ushort4 u;
            u.x = bfu(v.x); u.y = bfu(v.y); u.z = bfu(v.z); u.w = bfu(v.w);
            *(ushort4*)&xs[row * 64 + k4] = u;
        }
        __syncthreads();
        // GEMM1: z1[16n x 256c] per wave
        #pragma unroll 4
        for (int cb = 0; cb < 16; ++cb) {
            float bv = b1s[cb * 16 + cl];
            f32x4 a = {bv, bv, bv, bv};
            #pragma unroll
            for (int kc = 0; kc < 2; ++kc) {
                bf16x8 af = *(const bf16x8*)&xs[(nw + cl) * 64 + kc * 32 + lg * 8];
                bf16x8 bf = *(const bf16x8*)&W1s[(((cb << 1) + kc) * 64 + lane) * 8];
                a = __builtin_amdgcn_mfma_f32_16x16x32_bf16(af, bf, a, 0, 0, 0);
            }
            #pragma unroll
            for (int r = 0; r < 4; ++r)
                z1s[(nw + lg * 4 + r) * 256 + cb * 16 + cl] = bfu(fmaxf(a[r], 0.f));
        }
        __syncthreads();
        // GEMM2: cache A-frags, loop col-blocks
        bf16x8 af2[8];
        #pragma unroll
        for (int kc = 0; kc < 8; ++kc)
            af2[kc] = *(const bf16x8*)&z1s[(nw + cl) * 256 + kc * 32 + lg * 8];
        float p0 = 0.f, p1 = 0.f, p2 = 0.f, p3 = 0.f;
        #pragma unroll
        for (int cb = 0; cb < 8; ++cb) {
            float bv = b2s[cb * 16 + cl];
            f32x4 a = {bv, bv, bv, bv};
            #pragma unroll
            for (int kc = 0; kc < 8; ++kc) {
                bf16x8 bf = *(const bf16x8*)&W2s[(((cb << 3) + kc) * 64 + lane) * 8];
                a = __builtin_amdgcn_mfma_f32_16x16x32_bf16(af2[kc], bf, a, 0, 0, 0);
            }
            float w3v = w3s[cb * 16 + cl];
            p0 = fmaf(fmaxf(a[0], 0.f), w3v, p0);
            p1 = fmaf(fmaxf(a[1], 0.f), w3v, p1);
            p2 = fmaf(fmaxf(a[2], 0.f), w3v, p2);
            p3 = fmaf(fmaxf(a[3], 0.f), w3v, p3);
        }
        #pragma unroll
        for (int ofs = 1; ofs <= 8; ofs <<= 1) {
            p0 += __shfl_xor(p0, ofs, 64); p1 += __shfl_xor(p1, ofs, 64);
            p2 += __shfl_xor(p2, ofs, 64); p3 += __shfl_xor(p3, ofs, 64);
        }
        if (cl == 0) {
            int base = n0 + nw + lg * 4;
            if (base + 0 < NND) out[base + 0] = p0 + bb3;
            if (base + 1 < NND) out[base + 1] = p1 + bb3;
            if (base + 2 < NND) out[base + 2] = p2 + bb3;
            if (base + 3 < NND) out[base + 3] = p3 + bb3;
        }
    }
}

extern "C" void kernel_launch(void* const* d_in, const int* in_sizes, int n_in,
                              void* d_out, int out_size, void* d_ws, size_t ws_size,
                              hipStream_t stream) {
    const int*   x_cat   = (const int*)  d_in[0];
    const float* x_num   = (const float*)d_in[1];
    const float* x_coord = (const float*)d_in[2];
    const int*   eidx    = (const int*)  d_in[3];
    const float* emb     = (const float*)d_in[4];
    const float* fB      = (const float*)d_in[5];
    const float* pW      = (const float*)d_in[6];
    const float* pb      = (const float*)d_in[7];
    const float* gatW    = (const float*)d_in[8];
    const float* attS    = (const float*)d_in[9];
    const float* attD    = (const float*)d_in[10];
    const float* gatB    = (const float*)d_in[11];
    const float* bnG     = (const float*)d_in[12];
    const float* bnB     = (const float*)d_in[13];
    const float* W1      = (const float*)d_in[14];
    const float* b1      = (const float*)d_in[15];
    const float* W2      = (const float*)d_in[16];
    const float* b2      = (const float*)d_in[17];
    const float* W3      = (const float*)d_in[18];
    const float* b3      = (const float*)d_in[19];
    float* out = (float*)d_out;

    char* p = (char*)d_ws;
    float* x     = (float*)p;  p += (size_t)NND * HID * 4;
    float* y     = (float*)p;  p += (size_t)NND * 256 * 4;
    float* alphS = (float*)p;  p += (size_t)NND * NH * 4;
    float* alphD = (float*)p;  p += (size_t)NND * NH * 4;
    float* accum = (float*)p;  p += (size_t)NND * HID * 4;
    float* bnst  = (float*)p;  p += 512;
    float* va    = (float*)p;  p += 512 * 4;
    unsigned short* W1f = (unsigned short*)p; p += 16384 * 2;
    unsigned short* W2f = (unsigned short*)p; p += 32768 * 2;
    int*   deg   = (int*)p;    p += (size_t)NND * 4;
    int*   cur   = (int*)p;    p += (size_t)NND * 4;
    int*   off   = (int*)p;    p += (size_t)(NND + 1) * 4 + 4;
    int*   srcs  = (int*)p;    p += (size_t)ETOT * 4;

    // CSR build (graph constant across layers) + weight packing
    k_zero_deg<<<(NND + 255) / 256, 256, 0, stream>>>(deg);
    k_count<<<(ETOT + 255) / 256, 256, 0, stream>>>(eidx, deg);
    k_scan<<<1, 1024, 0, stream>>>(deg, off, cur);
    k_fill<<<(ETOT + 255) / 256, 256, 0, stream>>>(eidx, cur, srcs);
    k_packw<<<192, 256, 0, stream>>>(W1, W2, W1f, W2f);

    k_feat_proj<<<512, 256, 0, stream>>>(x_cat, x_num, x_coord, emb, fB, pW, pb, x);
    for (int l = 0; l < 2; ++l) {
        k_va<<<1, 512, 0, stream>>>(gatW + (size_t)l * HID * 256,
                                    attS + l * NH * HID, attD + l * NH * HID, va, bnst);
        k_alpha2<<<2048, 256, 0, stream>>>(x, va, alphS, alphD);
        k_aggregate_y<<<2048, 256, 0, stream>>>(off, srcs, alphS, alphD, x, y);
        k_transform<<<625, 256, 0, stream>>>(y, gatW + (size_t)l * HID * 256,
                                             gatB + l * HID, accum, bnst);
        k_bn_apply<<<3125, 256, 0, stream>>>(accum, bnst, bnG + l * HID, bnB + l * HID, x);
    }
    k_mlp_mfma<<<256, 256, 0, stream>>>(x, W1f, W2f, b1, b2, W3, b3, out);
}

// Round 6
// 451.178 us; speedup vs baseline: 1.9535x; 1.4035x over previous
//
#include <hip/hip_runtime.h>
#include <hip/hip_bf16.h>

#define NND 50000
#define NCATS 3
#define VOC 1000
#define EDIM 16
#define NNUMF 16
#define FMAP 32
#define FIN 128          // 3*16 + 16 + 64
#define HID 64
#define NH 4
#define EB 400000
#define ETOT 450000      // EB + NND self loops
#define M1 256
#define M2 128
#define EPS_BN 1e-5f
#define NB 196           // ceil(NND/256)

typedef __attribute__((ext_vector_type(8))) short bf16x8;
typedef __attribute__((ext_vector_type(4))) float f32x4;

__device__ __forceinline__ float lrelu(float x) { return x > 0.f ? x : 0.2f * x; }

__device__ __forceinline__ unsigned short bfu(float f) {
    unsigned u = __float_as_uint(f);
    unsigned r = (u + 0x7FFFu + ((u >> 16) & 1u)) >> 16;
    return (unsigned short)r;
}

// ================= CSR build (once; graph identical for both layers) =================
__global__ void k_zero_deg(int* __restrict__ deg) {
    int i = blockIdx.x * blockDim.x + threadIdx.x;
    if (i < NND) deg[i] = 0;
}

__global__ void k_count(const int* __restrict__ ei, int* __restrict__ deg) {
    int e = blockIdx.x * blockDim.x + threadIdx.x;
    if (e >= ETOT) return;
    int d = (e < EB) ? ei[EB + e] : e - EB;
    atomicAdd(&deg[d], 1);
}

// per-block sums of deg
__global__ __launch_bounds__(256) void k_bsum(const int* __restrict__ deg,
                                              int* __restrict__ bsum) {
    int i = blockIdx.x * 256 + threadIdx.x;
    int v = (i < NND) ? deg[i] : 0;
    #pragma unroll
    for (int ofs = 32; ofs; ofs >>= 1) v += __shfl_xor(v, ofs, 64);
    __shared__ int ws[4];
    if ((threadIdx.x & 63) == 0) ws[threadIdx.x >> 6] = v;
    __syncthreads();
    if (threadIdx.x == 0) bsum[blockIdx.x] = ws[0] + ws[1] + ws[2] + ws[3];
}

// single small block: exclusive scan of 196 block sums
__global__ __launch_bounds__(256) void k_bscan(const int* __restrict__ bsum,
                                               int* __restrict__ bpre,
                                               int* __restrict__ off) {
    __shared__ int sh[256];
    const int t = threadIdx.x;
    int v = (t < NB) ? bsum[t] : 0;
    sh[t] = v;
    __syncthreads();
    for (int ofs = 1; ofs < 256; ofs <<= 1) {
        int u = (t >= ofs) ? sh[t - ofs] : 0;
        __syncthreads();
        sh[t] += u;
        __syncthreads();
    }
    if (t < NB) bpre[t] = sh[t] - v;
    if (t == 0) off[NND] = ETOT;
}

// per-block exclusive scan + block prefix -> off, cur
__global__ __launch_bounds__(256) void k_offsets(const int* __restrict__ deg,
                                                 const int* __restrict__ bpre,
                                                 int* __restrict__ off,
                                                 int* __restrict__ cur) {
    __shared__ int sh[256];
    const int t = threadIdx.x;
    const int i = blockIdx.x * 256 + t;
    int v = (i < NND) ? deg[i] : 0;
    sh[t] = v;
    __syncthreads();
    for (int ofs = 1; ofs < 256; ofs <<= 1) {
        int u = (t >= ofs) ? sh[t - ofs] : 0;
        __syncthreads();
        sh[t] += u;
        __syncthreads();
    }
    int excl = sh[t] - v + bpre[blockIdx.x];
    if (i < NND) { off[i] = excl; cur[i] = excl; }
}

__global__ void k_fill(const int* __restrict__ ei, int* __restrict__ cur,
                       int* __restrict__ srcs) {
    int e = blockIdx.x * blockDim.x + threadIdx.x;
    if (e >= ETOT) return;
    int s, d;
    if (e < EB) { s = ei[e]; d = ei[EB + e]; } else { s = d = e - EB; }
    int p = atomicAdd(&cur[d], 1);
    srcs[p] = s;
}

// ============== pack W1/W2 into bf16 MFMA B-fragment order ==============
__global__ __launch_bounds__(256) void k_packw(
    const float* __restrict__ W1, const float* __restrict__ W2,
    unsigned short* __restrict__ W1f, unsigned short* __restrict__ W2f)
{
    int i = blockIdx.x * 256 + threadIdx.x;
    if (i < 16384) {
        int j = i & 7, l = (i >> 3) & 63, t = i >> 9;
        int kc = t & 1, cb = t >> 1;
        int k = kc * 32 + ((l >> 4) * 8) + j, c = cb * 16 + (l & 15);
        W1f[i] = bfu(W1[k * 256 + c]);
    }
    if (i < 32768) {
        int j = i & 7, l = (i >> 3) & 63, t = i >> 9;
        int kc = t & 7, cb = t >> 3;
        int k = kc * 32 + ((l >> 4) * 8) + j, c = cb * 16 + (l & 15);
        W2f[i] = bfu(W2[k * 128 + c]);
    }
}

// ================= K1: featurize + project (128 -> 64), 16-node tiles =================
__global__ __launch_bounds__(256) void k_feat_proj(
    const int* __restrict__ x_cat, const float* __restrict__ x_num,
    const float* __restrict__ x_coord, const float* __restrict__ emb,
    const float* __restrict__ fB, const float* __restrict__ pW,
    const float* __restrict__ pb, float* __restrict__ xout)
{
    __shared__ float Wl[FIN * HID];   // 32 KB
    __shared__ float feat[16][FIN];   // 8 KB
    const int tid = threadIdx.x;
    for (int i = tid; i < FIN * HID; i += 256) Wl[i] = pW[i];
    const int wid = tid >> 6, lane = tid & 63;
    const int col = lane, ng = wid;
    const float bias = pb[col];
    const int ntiles = NND / 16;
    for (int t = blockIdx.x; t < ntiles; t += gridDim.x) {
        const int n0 = t * 16;
        __syncthreads();
        #pragma unroll
        for (int r = 0; r < 4; ++r) {
            const int nn = wid * 4 + r;
            const int n = n0 + nn;
            float v;
            if (lane < 48) {
                int c = lane >> 4, j = lane & 15;
                int idx = x_cat[n * NCATS + c];
                v = emb[((size_t)c * VOC + idx) * EDIM + j];
            } else {
                v = x_num[n * NNUMF + (lane - 48)];
            }
            feat[nn][lane] = v;
            float c0 = x_coord[n * 2 + 0], c1 = x_coord[n * 2 + 1];
            int f = lane & 31;
            float xp = 6.283185307179586f * (c0 * fB[f] + c1 * fB[FMAP + f]);
            feat[nn][64 + lane] = (lane < 32) ? sinf(xp) : cosf(xp);
        }
        __syncthreads();
        float acc[4] = {bias, bias, bias, bias};
        #pragma unroll 4
        for (int k = 0; k < FIN; ++k) {
            float w = Wl[k * HID + col];
            #pragma unroll
            for (int j = 0; j < 4; ++j)
                acc[j] = fmaf(feat[ng + 4 * j][k], w, acc[j]);
        }
        #pragma unroll
        for (int j = 0; j < 4; ++j)
            xout[(size_t)(n0 + ng + 4 * j) * HID + col] = acc[j];
    }
}

// ================= K2a: va = W @ att (64x8) + zero bnst =================
__global__ __launch_bounds__(512) void k_va(
    const float* __restrict__ W, const float* __restrict__ aS,
    const float* __restrict__ aD, float* __restrict__ va, float* __restrict__ bnst)
{
    const int t = threadIdx.x;
    const int k = t >> 3, q = t & 7, hh = q & 3;
    const float* a = (q >= 4) ? aD : aS;
    float s = 0.f;
    #pragma unroll 8
    for (int d = 0; d < HID; ++d)
        s += W[k * 256 + hh * 64 + d] * a[hh * 64 + d];
    va[k * 8 + q] = s;
    if (t < 128) bnst[t] = 0.f;
}

// ================= K2b: alphas from x =================
__global__ __launch_bounds__(256) void k_alpha2(
    const float* __restrict__ x, const float* __restrict__ va,
    float* __restrict__ alphS, float* __restrict__ alphD)
{
    __shared__ float vas[64 * 8];
    const int tid = threadIdx.x;
    for (int i = tid; i < 512; i += 256) vas[i] = va[i];
    __syncthreads();
    const int lane = tid & 63, wid = tid >> 6;
    const float4 vS = *(const float4*)&vas[lane * 8];
    const float4 vD = *(const float4*)&vas[lane * 8 + 4];
    for (int n = blockIdx.x * 4 + wid; n < NND; n += gridDim.x * 4) {
        float v = x[(size_t)n * HID + lane];
        float s0 = v * vS.x, s1 = v * vS.y, s2 = v * vS.z, s3 = v * vS.w;
        float d0 = v * vD.x, d1 = v * vD.y, d2 = v * vD.z, d3 = v * vD.w;
        #pragma unroll
        for (int ofs = 32; ofs; ofs >>= 1) {
            s0 += __shfl_xor(s0, ofs, 64); s1 += __shfl_xor(s1, ofs, 64);
            s2 += __shfl_xor(s2, ofs, 64); s3 += __shfl_xor(s3, ofs, 64);
            d0 += __shfl_xor(d0, ofs, 64); d1 += __shfl_xor(d1, ofs, 64);
            d2 += __shfl_xor(d2, ofs, 64); d3 += __shfl_xor(d3, ofs, 64);
        }
        if (lane == 0) {
            *(float4*)(alphS + (size_t)n * 4) = make_float4(s0, s1, s2, s3);
            *(float4*)(alphD + (size_t)n * 4) = make_float4(d0, d1, d2, d3);
        }
    }
}

// ====== K3: aggregate x into per-head y (attention is linear) — 4-deep pipelined ======
__global__ __launch_bounds__(256) void k_aggregate_y(
    const int* __restrict__ off, const int* __restrict__ srcs,
    const float* __restrict__ alphS, const float* __restrict__ alphD,
    const float* __restrict__ x, float* __restrict__ y)
{
    const int lane = threadIdx.x & 63;
    int gw = blockIdx.x * 4 + (threadIdx.x >> 6);
    const int nw = gridDim.x * 4;
    for (int d = gw; d < NND; d += nw) {
        const int o0 = off[d], o1 = off[d + 1];
        const int deg = o1 - o0;
        const float4 ad = *(const float4*)(alphD + (size_t)d * 4);
        float dn0 = 0.f, dn1 = 0.f, dn2 = 0.f, dn3 = 0.f;
        int sE = 0; float w0 = 0.f, w1 = 0.f, w2 = 0.f, w3 = 0.f;
        for (int i = lane; i < deg; i += 64) {
            int s = srcs[o0 + i];
            float4 as = *(const float4*)(alphS + (size_t)s * 4);
            float e0 = __expf(lrelu(as.x + ad.x));
            float e1 = __expf(lrelu(as.y + ad.y));
            float e2 = __expf(lrelu(as.z + ad.z));
            float e3 = __expf(lrelu(as.w + ad.w));
            dn0 += e0; dn1 += e1; dn2 += e2; dn3 += e3;
            if (i < 64) { sE = s; w0 = e0; w1 = e1; w2 = e2; w3 = e3; }
        }
        #pragma unroll
        for (int ofs = 32; ofs; ofs >>= 1) {
            dn0 += __shfl_xor(dn0, ofs, 64); dn1 += __shfl_xor(dn1, ofs, 64);
            dn2 += __shfl_xor(dn2, ofs, 64); dn3 += __shfl_xor(dn3, ofs, 64);
        }
        const float i0 = __fdividef(1.f, dn0 + 1e-16f);
        const float i1 = __fdividef(1.f, dn1 + 1e-16f);
        const float i2 = __fdividef(1.f, dn2 + 1e-16f);
        const float i3 = __fdividef(1.f, dn3 + 1e-16f);
        float y0 = 0.f, y1 = 0.f, y2 = 0.f, y3 = 0.f;   // lane = x-dim k
        for (int c0 = 0; c0 < deg; c0 += 64) {
            const int m = min(64, deg - c0);
            if (c0 > 0) {
                sE = 0; w0 = w1 = w2 = w3 = 0.f;
                if (lane < m) {
                    sE = srcs[o0 + c0 + lane];
                    float4 as = *(const float4*)(alphS + (size_t)sE * 4);
                    w0 = __expf(lrelu(as.x + ad.x));
                    w1 = __expf(lrelu(as.y + ad.y));
                    w2 = __expf(lrelu(as.z + ad.z));
                    w3 = __expf(lrelu(as.w + ad.w));
                }
            }
            int j = 0;
            for (; j + 4 <= m; j += 4) {
                const int sj0 = __shfl(sE, j + 0, 64), sj1 = __shfl(sE, j + 1, 64);
                const int sj2 = __shfl(sE, j + 2, 64), sj3 = __shfl(sE, j + 3, 64);
                const float xv0 = x[(size_t)sj0 * HID + lane];
                const float xv1 = x[(size_t)sj1 * HID + lane];
                const float xv2 = x[(size_t)sj2 * HID + lane];
                const float xv3 = x[(size_t)sj3 * HID + lane];
                float a0, a1, a2, a3;
                a0 = __shfl(w0, j + 0, 64); a1 = __shfl(w1, j + 0, 64);
                a2 = __shfl(w2, j + 0, 64); a3 = __shfl(w3, j + 0, 64);
                y0 = fmaf(a0, xv0, y0); y1 = fmaf(a1, xv0, y1);
                y2 = fmaf(a2, xv0, y2); y3 = fmaf(a3, xv0, y3);
                a0 = __shfl(w0, j + 1, 64); a1 = __shfl(w1, j + 1, 64);
                a2 = __shfl(w2, j + 1, 64); a3 = __shfl(w3, j + 1, 64);
                y0 = fmaf(a0, xv1, y0); y1 = fmaf(a1, xv1, y1);
                y2 = fmaf(a2, xv1, y2); y3 = fmaf(a3, xv1, y3);
                a0 = __shfl(w0, j + 2, 64); a1 = __shfl(w1, j + 2, 64);
                a2 = __shfl(w2, j + 2, 64); a3 = __shfl(w3, j + 2, 64);
                y0 = fmaf(a0, xv2, y0); y1 = fmaf(a1, xv2, y1);
                y2 = fmaf(a2, xv2, y2); y3 = fmaf(a3, xv2, y3);
                a0 = __shfl(w0, j + 3, 64); a1 = __shfl(w1, j + 3, 64);
                a2 = __shfl(w2, j + 3, 64); a3 = __shfl(w3, j + 3, 64);
                y0 = fmaf(a0, xv3, y0); y1 = fmaf(a1, xv3, y1);
                y2 = fmaf(a2, xv3, y2); y3 = fmaf(a3, xv3, y3);
            }
            for (; j < m; ++j) {
                const int   sj = __shfl(sE, j, 64);
                const float a0 = __shfl(w0, j, 64), a1 = __shfl(w1, j, 64);
                const float a2 = __shfl(w2, j, 64), a3 = __shfl(w3, j, 64);
                const float xv = x[(size_t)sj * HID + lane];
                y0 = fmaf(a0, xv, y0); y1 = fmaf(a1, xv, y1);
                y2 = fmaf(a2, xv, y2); y3 = fmaf(a3, xv, y3);
            }
        }
        float* yd = y + (size_t)d * 256;
        yd[lane]       = y0 * i0;
        yd[64 + lane]  = y1 * i1;
        yd[128 + lane] = y2 * i2;
        yd[192 + lane] = y3 * i3;
    }
}

// ====== K4: out = 0.25*(y @ Ws) + b — Ws K-slice in REGISTERS, 32 KB LDS ======
__global__ __launch_bounds__(256) void k_transform(
    const float* __restrict__ y, const float* __restrict__ W,
    const float* __restrict__ gat_b, float* __restrict__ accum,
    float* __restrict__ bnst)
{
    __shared__ float ys[16 * 256];      // 16 KB
    __shared__ float part[4 * 16 * 64]; // 16 KB
    const int tid = threadIdx.x;
    const int col = tid & 63;
    const int ks = (tid >> 6) * 64;     // this wave's K-slice of stacked rows
    float wr[64];                       // Ws[ks+j][col] in registers
    #pragma unroll
    for (int j = 0; j < 64; ++j) {
        int r = ks + j;                 // r = h*64 + k
        wr[j] = W[(r & 63) * 256 + (r >> 6) * 64 + col];
    }
    const float bd = gat_b[col];
    float s1 = 0.f, s2 = 0.f;
    const int ntiles = NND / 16;
    for (int t = blockIdx.x; t < ntiles; t += gridDim.x) {
        const int n0 = t * 16;
        __syncthreads();
        {
            const float4* src = (const float4*)(y + (size_t)n0 * 256);
            float4* dst = (float4*)ys;
            #pragma unroll
            for (int q = 0; q < 4; ++q) dst[tid + q * 256] = src[tid + q * 256];
        }
        __syncthreads();
        float acc[16];
        #pragma unroll
        for (int n = 0; n < 16; ++n) acc[n] = 0.f;
        #pragma unroll
        for (int j = 0; j < 64; j += 4) {
            #pragma unroll
            for (int n = 0; n < 16; ++n) {
                float4 yv = *(const float4*)&ys[n * 256 + ks + j];
                acc[n] = fmaf(yv.x, wr[j], fmaf(yv.y, wr[j + 1],
                         fmaf(yv.z, wr[j + 2], fmaf(yv.w, wr[j + 3], acc[n]))));
            }
        }
        #pragma unroll
        for (int n = 0; n < 16; ++n)
            part[(tid >> 6) * 1024 + n * 64 + col] = acc[n];
        __syncthreads();
        const int ng = tid >> 6;
        #pragma unroll
        for (int i2 = 0; i2 < 4; ++i2) {
            int n = ng * 4 + i2;
            float g = part[n * 64 + col] + part[1024 + n * 64 + col]
                    + part[2048 + n * 64 + col] + part[3072 + n * 64 + col];
            g = g * 0.25f + bd;
            accum[(size_t)(n0 + n) * HID + col] = g;
            s1 += g; s2 += g * g;
        }
    }
    __syncthreads();
    part[tid] = s1; part[256 + tid] = s2;
    __syncthreads();
    if (tid < 64) {
        float a = part[tid] + part[tid + 64] + part[tid + 128] + part[tid + 192];
        float b = part[256 + tid] + part[256 + tid + 64] + part[256 + tid + 128]
                + part[256 + tid + 192];
        atomicAdd(&bnst[tid], a);
        atomicAdd(&bnst[64 + tid], b);
    }
}

// ================= K5: BN apply + relu + residual (float4, in place on x) =================
__global__ void k_bn_apply(const float* __restrict__ accum, const float* __restrict__ bnst,
                           const float* __restrict__ gamma, const float* __restrict__ beta,
                           float* __restrict__ x)
{
    int i = blockIdx.x * blockDim.x + threadIdx.x;   // float4 index
    if (i >= NND * 16) return;
    int dg = (i & 15) * 4;
    float4 a = ((const float4*)accum)[i];
    float4 xv = ((float4*)x)[i];
    float r[4]; float av[4] = {a.x, a.y, a.z, a.w}; float xx[4] = {xv.x, xv.y, xv.z, xv.w};
    #pragma unroll
    for (int c = 0; c < 4; ++c) {
        int d = dg + c;
        float mu = bnst[d] * (1.f / NND);
        float var = bnst[64 + d] * (1.f / NND) - mu * mu;
        float inv = rsqrtf(var + EPS_BN);
        float yv = (av[c] - mu) * inv * gamma[d] + beta[d];
        r[c] = fmaxf(yv, 0.f) + xx[c];
    }
    ((float4*)x)[i] = make_float4(r[0], r[1], r[2], r[3]);
}

// ====== K6: fused MFMA MLP ======
__global__ __launch_bounds__(256, 1) void k_mlp_mfma(
    const float* __restrict__ x,
    const unsigned short* __restrict__ W1f, const unsigned short* __restrict__ W2f,
    const float* __restrict__ b1, const float* __restrict__ b2,
    const float* __restrict__ W3, const float* __restrict__ b3,
    float* __restrict__ out)
{
    __shared__ __align__(16) unsigned short W1s[16384];  // 32 KB (frag order)
    __shared__ __align__(16) unsigned short W2s[32768];  // 64 KB (frag order)
    __shared__ __align__(16) unsigned short xs[64 * 64]; // 8 KB
    __shared__ __align__(16) unsigned short z1s[64 * 256]; // 32 KB
    __shared__ float b1s[256], b2s[128], w3s[128];
    const int tid = threadIdx.x;
    const int lane = tid & 63, wid = tid >> 6;
    {
        const uint4* s1 = (const uint4*)W1f; uint4* d1 = (uint4*)W1s;
        for (int i = tid; i < 2048; i += 256) d1[i] = s1[i];
        const uint4* s2 = (const uint4*)W2f; uint4* d2 = (uint4*)W2s;
        for (int i = tid; i < 4096; i += 256) d2[i] = s2[i];
        if (tid < 256) b1s[tid] = b1[tid];
        if (tid < 128) { b2s[tid] = b2[tid]; w3s[tid] = W3[tid]; }
    }
    const float bb3 = b3[0];
    const int nw = wid * 16;
    const int cl = lane & 15, lg = lane >> 4;
    const int ntiles = (NND + 63) / 64;
    for (int t = blockIdx.x; t < ntiles; t += gridDim.x) {
        const int n0 = t * 64;
        __syncthreads();
        #pragma unroll
        for (int q = 0; q < 4; ++q) {
            int i = q * 256 + tid;
            int row = i >> 4, k4 = (i & 15) * 4;
            int n = n0 + row;
            float4 v = (n < NND) ? *(const float4*)(x + (size_t)n * HID + k4)
                                 : make_float4(0.f, 0.f, 0.f, 0.f);
            ushort4 u;
            u.x = bfu(v.x); u.y = bfu(v.y); u.z = bfu(v.z); u.w = bfu(v.w);
            *(ushort4*)&xs[row * 64 + k4] = u;
        }
        __syncthreads();
        #pragma unroll 4
        for (int cb = 0; cb < 16; ++cb) {
            float bv = b1s[cb * 16 + cl];
            f32x4 a = {bv, bv, bv, bv};
            #pragma unroll
            for (int kc = 0; kc < 2; ++kc) {
                bf16x8 af = *(const bf16x8*)&xs[(nw + cl) * 64 + kc * 32 + lg * 8];
                bf16x8 bf = *(const bf16x8*)&W1s[(((cb << 1) + kc) * 64 + lane) * 8];
                a = __builtin_amdgcn_mfma_f32_16x16x32_bf16(af, bf, a, 0, 0, 0);
            }
            #pragma unroll
            for (int r = 0; r < 4; ++r)
                z1s[(nw + lg * 4 + r) * 256 + cb * 16 + cl] = bfu(fmaxf(a[r], 0.f));
        }
        __syncthreads();
        bf16x8 af2[8];
        #pragma unroll
        for (int kc = 0; kc < 8; ++kc)
            af2[kc] = *(const bf16x8*)&z1s[(nw + cl) * 256 + kc * 32 + lg * 8];
        float p0 = 0.f, p1 = 0.f, p2 = 0.f, p3 = 0.f;
        #pragma unroll
        for (int cb = 0; cb < 8; ++cb) {
            float bv = b2s[cb * 16 + cl];
            f32x4 a = {bv, bv, bv, bv};
            #pragma unroll
            for (int kc = 0; kc < 8; ++kc) {
                bf16x8 bf = *(const bf16x8*)&W2s[(((cb << 3) + kc) * 64 + lane) * 8];
                a = __builtin_amdgcn_mfma_f32_16x16x32_bf16(af2[kc], bf, a, 0, 0, 0);
            }
            float w3v = w3s[cb * 16 + cl];
            p0 = fmaf(fmaxf(a[0], 0.f), w3v, p0);
            p1 = fmaf(fmaxf(a[1], 0.f), w3v, p1);
            p2 = fmaf(fmaxf(a[2], 0.f), w3v, p2);
            p3 = fmaf(fmaxf(a[3], 0.f), w3v, p3);
        }
        #pragma unroll
        for (int ofs = 1; ofs <= 8; ofs <<= 1) {
            p0 += __shfl_xor(p0, ofs, 64); p1 += __shfl_xor(p1, ofs, 64);
            p2 += __shfl_xor(p2, ofs, 64); p3 += __shfl_xor(p3, ofs, 64);
        }
        if (cl == 0) {
            int base = n0 + nw + lg * 4;
            if (base + 0 < NND) out[base + 0] = p0 + bb3;
            if (base + 1 < NND) out[base + 1] = p1 + bb3;
            if (base + 2 < NND) out[base + 2] = p2 + bb3;
            if (base + 3 < NND) out[base + 3] = p3 + bb3;
        }
    }
}

extern "C" void kernel_launch(void* const* d_in, const int* in_sizes, int n_in,
                              void* d_out, int out_size, void* d_ws, size_t ws_size,
                              hipStream_t stream) {
    const int*   x_cat   = (const int*)  d_in[0];
    const float* x_num   = (const float*)d_in[1];
    const float* x_coord = (const float*)d_in[2];
    const int*   eidx    = (const int*)  d_in[3];
    const float* emb     = (const float*)d_in[4];
    const float* fB      = (const float*)d_in[5];
    const float* pW      = (const float*)d_in[6];
    const float* pb      = (const float*)d_in[7];
    const float* gatW    = (const float*)d_in[8];
    const float* attS    = (const float*)d_in[9];
    const float* attD    = (const float*)d_in[10];
    const float* gatB    = (const float*)d_in[11];
    const float* bnG     = (const float*)d_in[12];
    const float* bnB     = (const float*)d_in[13];
    const float* W1      = (const float*)d_in[14];
    const float* b1      = (const float*)d_in[15];
    const float* W2      = (const float*)d_in[16];
    const float* b2      = (const float*)d_in[17];
    const float* W3      = (const float*)d_in[18];
    const float* b3      = (const float*)d_in[19];
    float* out = (float*)d_out;

    char* p = (char*)d_ws;
    float* x     = (float*)p;  p += (size_t)NND * HID * 4;
    float* y     = (float*)p;  p += (size_t)NND * 256 * 4;
    float* alphS = (float*)p;  p += (size_t)NND * NH * 4;
    float* alphD = (float*)p;  p += (size_t)NND * NH * 4;
    float* accum = (float*)p;  p += (size_t)NND * HID * 4;
    float* bnst  = (float*)p;  p += 512;
    float* va    = (float*)p;  p += 512 * 4;
    unsigned short* W1f = (unsigned short*)p; p += 16384 * 2;
    unsigned short* W2f = (unsigned short*)p; p += 32768 * 2;
    int*   deg   = (int*)p;    p += (size_t)NND * 4;
    int*   cur   = (int*)p;    p += (size_t)NND * 4;
    int*   off   = (int*)p;    p += (size_t)(NND + 1) * 4 + 4;
    int*   srcs  = (int*)p;    p += (size_t)ETOT * 4;
    int*   bsum  = (int*)p;    p += NB * 4;
    int*   bpre  = (int*)p;    p += NB * 4;

    // CSR build (graph constant across layers) + weight packing
    k_zero_deg<<<NB, 256, 0, stream>>>(deg);
    k_count<<<(ETOT + 255) / 256, 256, 0, stream>>>(eidx, deg);
    k_bsum<<<NB, 256, 0, stream>>>(deg, bsum);
    k_bscan<<<1, 256, 0, stream>>>(bsum, bpre, off);
    k_offsets<<<NB, 256, 0, stream>>>(deg, bpre, off, cur);
    k_fill<<<(ETOT + 255) / 256, 256, 0, stream>>>(eidx, cur, srcs);
    k_packw<<<192, 256, 0, stream>>>(W1, W2, W1f, W2f);

    k_feat_proj<<<512, 256, 0, stream>>>(x_cat, x_num, x_coord, emb, fB, pW, pb, x);
    for (int l = 0; l < 2; ++l) {
        k_va<<<1, 512, 0, stream>>>(gatW + (size_t)l * HID * 256,
                                    attS + l * NH * HID, attD + l * NH * HID, va, bnst);
        k_alpha2<<<2048, 256, 0, stream>>>(x, va, alphS, alphD);
        k_aggregate_y<<<2048, 256, 0, stream>>>(off, srcs, alphS, alphD, x, y);
        k_transform<<<625, 256, 0, stream>>>(y, gatW + (size_t)l * HID * 256,
                                             gatB + l * HID, accum, bnst);
        k_bn_apply<<<3125, 256, 0, stream>>>(accum, bnst, bnG + l * HID, bnB + l * HID, x);
    }
    k_mlp_mfma<<<256, 256, 0, stream>>>(x, W1f, W2f, b1, b2, W3, b3, out);
}

// Round 8
// 407.914 us; speedup vs baseline: 2.1607x; 1.1061x over previous
//
#include <hip/hip_runtime.h>
#include <hip/hip_bf16.h>

#define NND 50000
#define NCATS 3
#define VOC 1000
#define EDIM 16
#define NNUMF 16
#define FMAP 32
#define FIN 128          // 3*16 + 16 + 64
#define HID 64
#define NH 4
#define EB 400000
#define ETOT 450000      // EB + NND self loops
#define M1 256
#define M2 128
#define EPS_BN 1e-5f
#define NB 196           // ceil(NND/256)

typedef __attribute__((ext_vector_type(8))) short bf16x8;
typedef __attribute__((ext_vector_type(4))) float f32x4;

__device__ __forceinline__ float lrelu(float x) { return x > 0.f ? x : 0.2f * x; }

__device__ __forceinline__ unsigned short bfu(float f) {
    unsigned u = __float_as_uint(f);
    unsigned r = (u + 0x7FFFu + ((u >> 16) & 1u)) >> 16;
    return (unsigned short)r;
}
__device__ __forceinline__ float bf2f(unsigned short h) {
    return __uint_as_float((unsigned)h << 16);
}

// ================= CSR build (once; graph identical for both layers) =================
__global__ void k_zero_deg(int* __restrict__ deg) {
    int i = blockIdx.x * blockDim.x + threadIdx.x;
    if (i < NND) deg[i] = 0;
}

__global__ void k_count(const int* __restrict__ ei, int* __restrict__ deg) {
    int e = blockIdx.x * blockDim.x + threadIdx.x;
    if (e >= ETOT) return;
    int d = (e < EB) ? ei[EB + e] : e - EB;
    atomicAdd(&deg[d], 1);
}

__global__ __launch_bounds__(256) void k_bsum(const int* __restrict__ deg,
                                              int* __restrict__ bsum) {
    int i = blockIdx.x * 256 + threadIdx.x;
    int v = (i < NND) ? deg[i] : 0;
    #pragma unroll
    for (int ofs = 32; ofs; ofs >>= 1) v += __shfl_xor(v, ofs, 64);
    __shared__ int ws[4];
    if ((threadIdx.x & 63) == 0) ws[threadIdx.x >> 6] = v;
    __syncthreads();
    if (threadIdx.x == 0) bsum[blockIdx.x] = ws[0] + ws[1] + ws[2] + ws[3];
}

__global__ __launch_bounds__(256) void k_bscan(const int* __restrict__ bsum,
                                               int* __restrict__ bpre,
                                               int* __restrict__ off) {
    __shared__ int sh[256];
    const int t = threadIdx.x;
    int v = (t < NB) ? bsum[t] : 0;
    sh[t] = v;
    __syncthreads();
    for (int ofs = 1; ofs < 256; ofs <<= 1) {
        int u = (t >= ofs) ? sh[t - ofs] : 0;
        __syncthreads();
        sh[t] += u;
        __syncthreads();
    }
    if (t < NB) bpre[t] = sh[t] - v;
    if (t == 0) off[NND] = ETOT;
}

__global__ __launch_bounds__(256) void k_offsets(const int* __restrict__ deg,
                                                 const int* __restrict__ bpre,
                                                 int* __restrict__ off,
                                                 int* __restrict__ cur) {
    __shared__ int sh[256];
    const int t = threadIdx.x;
    const int i = blockIdx.x * 256 + t;
    int v = (i < NND) ? deg[i] : 0;
    sh[t] = v;
    __syncthreads();
    for (int ofs = 1; ofs < 256; ofs <<= 1) {
        int u = (t >= ofs) ? sh[t - ofs] : 0;
        __syncthreads();
        sh[t] += u;
        __syncthreads();
    }
    int excl = sh[t] - v + bpre[blockIdx.x];
    if (i < NND) { off[i] = excl; cur[i] = excl; }
}

__global__ void k_fill(const int* __restrict__ ei, int* __restrict__ cur,
                       int* __restrict__ srcs) {
    int e = blockIdx.x * blockDim.x + threadIdx.x;
    if (e >= ETOT) return;
    int s, d;
    if (e < EB) { s = ei[e]; d = ei[EB + e]; } else { s = d = e - EB; }
    int p = atomicAdd(&cur[d], 1);
    srcs[p] = s;
}

// ===== pack W1/W2 (bf16) and Ws (stacked gatW, both layers, hi+lo split) into MFMA B-frag order =====
__global__ __launch_bounds__(256) void k_packw(
    const float* __restrict__ W1, const float* __restrict__ W2,
    const float* __restrict__ gatW,
    unsigned short* __restrict__ W1f, unsigned short* __restrict__ W2f,
    unsigned short* __restrict__ Wsf, unsigned short* __restrict__ Wsl)
{
    int i = blockIdx.x * 256 + threadIdx.x;
    if (i < 16384) {
        int j = i & 7, l = (i >> 3) & 63, t = i >> 9;
        int kc = t & 1, cb = t >> 1;
        int k = kc * 32 + ((l >> 4) * 8) + j, c = cb * 16 + (l & 15);
        W1f[i] = bfu(W1[k * 256 + c]);
    }
    if (i < 32768) {
        int j = i & 7, l = (i >> 3) & 63, t = i >> 9;
        int kc = t & 7, cb = t >> 3;
        int k = kc * 32 + ((l >> 4) * 8) + j, c = cb * 16 + (l & 15);
        W2f[i] = bfu(W2[k * 128 + c]);
    }
    if (i < 32768) {   // Ws: 2 layers x (4 cb x 8 kc); Ws[r][c] = W[r&63][(r>>6)*64+c]
        int j = i & 7, l = (i >> 3) & 63, t = (i >> 9) & 31, lay = i >> 14;
        int kc = t & 7, cb = t >> 3;
        int r = kc * 32 + ((l >> 4) * 8) + j, c = cb * 16 + (l & 15);
        float w = gatW[lay * 16384 + (r & 63) * 256 + (r >> 6) * 64 + c];
        unsigned short h = bfu(w);
        Wsf[i] = h;
        Wsl[i] = bfu(w - bf2f(h));
    }
}

// ================= K1: featurize + project (128 -> 64), 16-node tiles =================
__global__ __launch_bounds__(256) void k_feat_proj(
    const int* __restrict__ x_cat, const float* __restrict__ x_num,
    const float* __restrict__ x_coord, const float* __restrict__ emb,
    const float* __restrict__ fB, const float* __restrict__ pW,
    const float* __restrict__ pb, float* __restrict__ xout)
{
    __shared__ float Wl[FIN * HID];   // 32 KB
    __shared__ float feat[16][FIN];   // 8 KB
    const int tid = threadIdx.x;
    for (int i = tid; i < FIN * HID; i += 256) Wl[i] = pW[i];
    const int wid = tid >> 6, lane = tid & 63;
    const int col = lane, ng = wid;
    const float bias = pb[col];
    const int ntiles = NND / 16;
    for (int t = blockIdx.x; t < ntiles; t += gridDim.x) {
        const int n0 = t * 16;
        __syncthreads();
        #pragma unroll
        for (int r = 0; r < 4; ++r) {
            const int nn = wid * 4 + r;
            const int n = n0 + nn;
            float v;
            if (lane < 48) {
                int c = lane >> 4, j = lane & 15;
                int idx = x_cat[n * NCATS + c];
                v = emb[((size_t)c * VOC + idx) * EDIM + j];
            } else {
                v = x_num[n * NNUMF + (lane - 48)];
            }
            feat[nn][lane] = v;
            float c0 = x_coord[n * 2 + 0], c1 = x_coord[n * 2 + 1];
            int f = lane & 31;
            float xp = 6.283185307179586f * (c0 * fB[f] + c1 * fB[FMAP + f]);
            feat[nn][64 + lane] = (lane < 32) ? sinf(xp) : cosf(xp);
        }
        __syncthreads();
        float acc[4] = {bias, bias, bias, bias};
        #pragma unroll 4
        for (int k = 0; k < FIN; ++k) {
            float w = Wl[k * HID + col];
            #pragma unroll
            for (int j = 0; j < 4; ++j)
                acc[j] = fmaf(feat[ng + 4 * j][k], w, acc[j]);
        }
        #pragma unroll
        for (int j = 0; j < 4; ++j)
            xout[(size_t)(n0 + ng + 4 * j) * HID + col] = acc[j];
    }
}

// ================= K2a: va = W @ att (64x8) + zero bnst (ALL 256 slots) =================
__global__ __launch_bounds__(512) void k_va(
    const float* __restrict__ W, const float* __restrict__ aS,
    const float* __restrict__ aD, float* __restrict__ va, float* __restrict__ bnst)
{
    const int t = threadIdx.x;
    const int k = t >> 3, q = t & 7, hh = q & 3;
    const float* a = (q >= 4) ? aD : aS;
    float s = 0.f;
    #pragma unroll 8
    for (int d = 0; d < HID; ++d)
        s += W[k * 256 + hh * 64 + d] * a[hh * 64 + d];
    va[k * 8 + q] = s;
    if (t < 256) bnst[t] = 0.f;
}

// ================= K2b: alphas from x =================
__global__ __launch_bounds__(256) void k_alpha2(
    const float* __restrict__ x, const float* __restrict__ va,
    float* __restrict__ alphS, float* __restrict__ alphD)
{
    __shared__ float vas[64 * 8];
    const int tid = threadIdx.x;
    for (int i = tid; i < 512; i += 256) vas[i] = va[i];
    __syncthreads();
    const int lane = tid & 63, wid = tid >> 6;
    const float4 vS = *(const float4*)&vas[lane * 8];
    const float4 vD = *(const float4*)&vas[lane * 8 + 4];
    for (int n = blockIdx.x * 4 + wid; n < NND; n += gridDim.x * 4) {
        float v = x[(size_t)n * HID + lane];
        float s0 = v * vS.x, s1 = v * vS.y, s2 = v * vS.z, s3 = v * vS.w;
        float d0 = v * vD.x, d1 = v * vD.y, d2 = v * vD.z, d3 = v * vD.w;
        #pragma unroll
        for (int ofs = 32; ofs; ofs >>= 1) {
            s0 += __shfl_xor(s0, ofs, 64); s1 += __shfl_xor(s1, ofs, 64);
            s2 += __shfl_xor(s2, ofs, 64); s3 += __shfl_xor(s3, ofs, 64);
            d0 += __shfl_xor(d0, ofs, 64); d1 += __shfl_xor(d1, ofs, 64);
            d2 += __shfl_xor(d2, ofs, 64); d3 += __shfl_xor(d3, ofs, 64);
        }
        if (lane == 0) {
            *(float4*)(alphS + (size_t)n * 4) = make_float4(s0, s1, s2, s3);
            *(float4*)(alphD + (size_t)n * 4) = make_float4(d0, d1, d2, d3);
        }
    }
}

// ====== K3: aggregate x into per-head y (split bf16 hi/lo out), 4-deep pipelined ======
__global__ __launch_bounds__(256) void k_aggregate_y(
    const int* __restrict__ off, const int* __restrict__ srcs,
    const float* __restrict__ alphS, const float* __restrict__ alphD,
    const float* __restrict__ x, unsigned short* __restrict__ yh,
    unsigned short* __restrict__ yl)
{
    const int lane = threadIdx.x & 63;
    int gw = blockIdx.x * 4 + (threadIdx.x >> 6);
    const int nw = gridDim.x * 4;
    for (int d = gw; d < NND; d += nw) {
        const int o0 = off[d], o1 = off[d + 1];
        const int deg = o1 - o0;
        const float4 ad = *(const float4*)(alphD + (size_t)d * 4);
        float dn0 = 0.f, dn1 = 0.f, dn2 = 0.f, dn3 = 0.f;
        int sE = 0; float w0 = 0.f, w1 = 0.f, w2 = 0.f, w3 = 0.f;
        for (int i = lane; i < deg; i += 64) {
            int s = srcs[o0 + i];
            float4 as = *(const float4*)(alphS + (size_t)s * 4);
            float e0 = __expf(lrelu(as.x + ad.x));
            float e1 = __expf(lrelu(as.y + ad.y));
            float e2 = __expf(lrelu(as.z + ad.z));
            float e3 = __expf(lrelu(as.w + ad.w));
            dn0 += e0; dn1 += e1; dn2 += e2; dn3 += e3;
            if (i < 64) { sE = s; w0 = e0; w1 = e1; w2 = e2; w3 = e3; }
        }
        #pragma unroll
        for (int ofs = 32; ofs; ofs >>= 1) {
            dn0 += __shfl_xor(dn0, ofs, 64); dn1 += __shfl_xor(dn1, ofs, 64);
            dn2 += __shfl_xor(dn2, ofs, 64); dn3 += __shfl_xor(dn3, ofs, 64);
        }
        const float i0 = __fdividef(1.f, dn0 + 1e-16f);
        const float i1 = __fdividef(1.f, dn1 + 1e-16f);
        const float i2 = __fdividef(1.f, dn2 + 1e-16f);
        const float i3 = __fdividef(1.f, dn3 + 1e-16f);
        float y0 = 0.f, y1 = 0.f, y2 = 0.f, y3 = 0.f;   // lane = x-dim k
        for (int c0 = 0; c0 < deg; c0 += 64) {
            const int m = min(64, deg - c0);
            if (c0 > 0) {
                sE = 0; w0 = w1 = w2 = w3 = 0.f;
                if (lane < m) {
                    sE = srcs[o0 + c0 + lane];
                    float4 as = *(const float4*)(alphS + (size_t)sE * 4);
                    w0 = __expf(lrelu(as.x + ad.x));
                    w1 = __expf(lrelu(as.y + ad.y));
                    w2 = __expf(lrelu(as.z + ad.z));
                    w3 = __expf(lrelu(as.w + ad.w));
                }
            }
            int j = 0;
            for (; j + 4 <= m; j += 4) {
                const int sj0 = __shfl(sE, j + 0, 64), sj1 = __shfl(sE, j + 1, 64);
                const int sj2 = __shfl(sE, j + 2, 64), sj3 = __shfl(sE, j + 3, 64);
                const float xv0 = x[(size_t)sj0 * HID + lane];
                const float xv1 = x[(size_t)sj1 * HID + lane];
                const float xv2 = x[(size_t)sj2 * HID + lane];
                const float xv3 = x[(size_t)sj3 * HID + lane];
                float a0, a1, a2, a3;
                a0 = __shfl(w0, j + 0, 64); a1 = __shfl(w1, j + 0, 64);
                a2 = __shfl(w2, j + 0, 64); a3 = __shfl(w3, j + 0, 64);
                y0 = fmaf(a0, xv0, y0); y1 = fmaf(a1, xv0, y1);
                y2 = fmaf(a2, xv0, y2); y3 = fmaf(a3, xv0, y3);
                a0 = __shfl(w0, j + 1, 64); a1 = __shfl(w1, j + 1, 64);
                a2 = __shfl(w2, j + 1, 64); a3 = __shfl(w3, j + 1, 64);
                y0 = fmaf(a0, xv1, y0); y1 = fmaf(a1, xv1, y1);
                y2 = fmaf(a2, xv1, y2); y3 = fmaf(a3, xv1, y3);
                a0 = __shfl(w0, j + 2, 64); a1 = __shfl(w1, j + 2, 64);
                a2 = __shfl(w2, j + 2, 64); a3 = __shfl(w3, j + 2, 64);
                y0 = fmaf(a0, xv2, y0); y1 = fmaf(a1, xv2, y1);
                y2 = fmaf(a2, xv2, y2); y3 = fmaf(a3, xv2, y3);
                a0 = __shfl(w0, j + 3, 64); a1 = __shfl(w1, j + 3, 64);
                a2 = __shfl(w2, j + 3, 64); a3 = __shfl(w3, j + 3, 64);
                y0 = fmaf(a0, xv3, y0); y1 = fmaf(a1, xv3, y1);
                y2 = fmaf(a2, xv3, y2); y3 = fmaf(a3, xv3, y3);
            }
            for (; j < m; ++j) {
                const int   sj = __shfl(sE, j, 64);
                const float a0 = __shfl(w0, j, 64), a1 = __shfl(w1, j, 64);
                const float a2 = __shfl(w2, j, 64), a3 = __shfl(w3, j, 64);
                const float xv = x[(size_t)sj * HID + lane];
                y0 = fmaf(a0, xv, y0); y1 = fmaf(a1, xv, y1);
                y2 = fmaf(a2, xv, y2); y3 = fmaf(a3, xv, y3);
            }
        }
        unsigned short* yhd = yh + (size_t)d * 256;
        unsigned short* yld = yl + (size_t)d * 256;
        float v;
        unsigned short h;
        v = y0 * i0; h = bfu(v); yhd[lane] = h;       yld[lane] = bfu(v - bf2f(h));
        v = y1 * i1; h = bfu(v); yhd[64 + lane] = h;  yld[64 + lane] = bfu(v - bf2f(h));
        v = y2 * i2; h = bfu(v); yhd[128 + lane] = h; yld[128 + lane] = bfu(v - bf2f(h));
        v = y3 * i3; h = bfu(v); yhd[192 + lane] = h; yld[192 + lane] = bfu(v - bf2f(h));
    }
}

// ====== K4: MFMA transform (split bf16): accum = 0.25*(y @ Ws) + b, + BN stats ======
// wave = one 16-col block (cb = wid); all 4 waves share the same node group.
__global__ __launch_bounds__(256) void k_transform_mfma(
    const unsigned short* __restrict__ yh, const unsigned short* __restrict__ yl,
    const unsigned short* __restrict__ Wh, const unsigned short* __restrict__ Wl_,
    const float* __restrict__ gat_b, float* __restrict__ accum,
    float* __restrict__ bnst)
{
    __shared__ float sred[2][4][16];
    const int tid = threadIdx.x;
    const int lane = tid & 63, wid = tid >> 6;   // wid = cb
    const int cl = lane & 15, lg = lane >> 4;
    bf16x8 wfh[8], wfl[8];
    #pragma unroll
    for (int kc = 0; kc < 8; ++kc) {
        wfh[kc] = *(const bf16x8*)&Wh[(size_t)(((wid << 3) + kc) * 64 + lane) * 8];
        wfl[kc] = *(const bf16x8*)&Wl_[(size_t)(((wid << 3) + kc) * 64 + lane) * 8];
    }
    const float bd = gat_b[wid * 16 + cl];
    float s1 = 0.f, s2 = 0.f;
    const int ngrp = NND / 16;   // 3125
    for (int g = blockIdx.x; g < ngrp; g += gridDim.x) {
        const int n0 = g * 16;
        bf16x8 afh[8], afl[8];
        #pragma unroll
        for (int kc = 0; kc < 8; ++kc) {
            afh[kc] = *(const bf16x8*)&yh[(size_t)(n0 + cl) * 256 + kc * 32 + lg * 8];
            afl[kc] = *(const bf16x8*)&yl[(size_t)(n0 + cl) * 256 + kc * 32 + lg * 8];
        }
        f32x4 a = {0.f, 0.f, 0.f, 0.f};
        #pragma unroll
        for (int kc = 0; kc < 8; ++kc)
            a = __builtin_amdgcn_mfma_f32_16x16x32_bf16(afl[kc], wfh[kc], a, 0, 0, 0);
        #pragma unroll
        for (int kc = 0; kc < 8; ++kc)
            a = __builtin_amdgcn_mfma_f32_16x16x32_bf16(afh[kc], wfl[kc], a, 0, 0, 0);
        #pragma unroll
        for (int kc = 0; kc < 8; ++kc)
            a = __builtin_amdgcn_mfma_f32_16x16x32_bf16(afh[kc], wfh[kc], a, 0, 0, 0);
        #pragma unroll
        for (int r = 0; r < 4; ++r) {
            float gv = a[r] * 0.25f + bd;
            accum[(size_t)(n0 + lg * 4 + r) * HID + wid * 16 + cl] = gv;
            s1 += gv; s2 += gv * gv;
        }
    }
    s1 += __shfl_xor(s1, 16, 64); s2 += __shfl_xor(s2, 16, 64);
    s1 += __shfl_xor(s1, 32, 64); s2 += __shfl_xor(s2, 32, 64);
    if (lane < 16) { sred[0][wid][cl] = s1; sred[1][wid][cl] = s2; }
    __syncthreads();
    if (tid < 64) {
        atomicAdd(&bnst[tid], sred[0][tid >> 4][tid & 15]);
        atomicAdd(&bnst[128 + tid], sred[1][tid >> 4][tid & 15]);
    }
}

// ================= K5: BN apply + relu + residual (float4, in place on x) =================
__global__ void k_bn_apply(const float* __restrict__ accum, const float* __restrict__ bnst,
                           const float* __restrict__ gamma, const float* __restrict__ beta,
                           float* __restrict__ x)
{
    int i = blockIdx.x * blockDim.x + threadIdx.x;   // float4 index
    if (i >= NND * 16) return;
    int dg = (i & 15) * 4;
    float4 a = ((const float4*)accum)[i];
    float4 xv = ((float4*)x)[i];
    float r[4]; float av[4] = {a.x, a.y, a.z, a.w}; float xx[4] = {xv.x, xv.y, xv.z, xv.w};
    #pragma unroll
    for (int c = 0; c < 4; ++c) {
        int d = dg + c;
        float mu = bnst[d] * (1.f / NND);
        float var = bnst[128 + d] * (1.f / NND) - mu * mu;
        float inv = rsqrtf(var + EPS_BN);
        float yv = (av[c] - mu) * inv * gamma[d] + beta[d];
        r[c] = fmaxf(yv, 0.f) + xx[c];
    }
    ((float4*)x)[i] = make_float4(r[0], r[1], r[2], r[3]);
}

// ====== K6: fused MFMA MLP ======
__global__ __launch_bounds__(256, 1) void k_mlp_mfma(
    const float* __restrict__ x,
    const unsigned short* __restrict__ W1f, const unsigned short* __restrict__ W2f,
    const float* __restrict__ b1, const float* __restrict__ b2,
    const float* __restrict__ W3, const float* __restrict__ b3,
    float* __restrict__ out)
{
    __shared__ __align__(16) unsigned short W1s[16384];  // 32 KB (frag order)
    __shared__ __align__(16) unsigned short W2s[32768];  // 64 KB (frag order)
    __shared__ __align__(16) unsigned short xs[64 * 64]; // 8 KB
    __shared__ __align__(16) unsigned short z1s[64 * 256]; // 32 KB
    __shared__ float b1s[256], b2s[128], w3s[128];
    const int tid = threadIdx.x;
    const int lane = tid & 63, wid = tid >> 6;
    {
        const uint4* s1 = (const uint4*)W1f; uint4* d1 = (uint4*)W1s;
        for (int i = tid; i < 2048; i += 256) d1[i] = s1[i];
        const uint4* s2 = (const uint4*)W2f; uint4* d2 = (uint4*)W2s;
        for (int i = tid; i < 4096; i += 256) d2[i] = s2[i];
        if (tid < 256) b1s[tid] = b1[tid];
        if (tid < 128) { b2s[tid] = b2[tid]; w3s[tid] = W3[tid]; }
    }
    const float bb3 = b3[0];
    const int nw = wid * 16;
    const int cl = lane & 15, lg = lane >> 4;
    const int ntiles = (NND + 63) / 64;
    for (int t = blockIdx.x; t < ntiles; t += gridDim.x) {
        const int n0 = t * 64;
        __syncthreads();
        #pragma unroll
        for (int q = 0; q < 4; ++q) {
            int i = q * 256 + tid;
            int row = i >> 4, k4 = (i & 15) * 4;
            int n = n0 + row;
            float4 v = (n < NND) ? *(const float4*)(x + (size_t)n * HID + k4)
                                 : make_float4(0.f, 0.f, 0.f, 0.f);
            ushort4 u;
            u.x = bfu(v.x); u.y = bfu(v.y); u.z = bfu(v.z); u.w = bfu(v.w);
            *(ushort4*)&xs[row * 64 + k4] = u;
        }
        __syncthreads();
        #pragma unroll 4
        for (int cb = 0; cb < 16; ++cb) {
            float bv = b1s[cb * 16 + cl];
            f32x4 a = {bv, bv, bv, bv};
            #pragma unroll
            for (int kc = 0; kc < 2; ++kc) {
                bf16x8 af = *(const bf16x8*)&xs[(nw + cl) * 64 + kc * 32 + lg * 8];
                bf16x8 bf = *(const bf16x8*)&W1s[(((cb << 1) + kc) * 64 + lane) * 8];
                a = __builtin_amdgcn_mfma_f32_16x16x32_bf16(af, bf, a, 0, 0, 0);
            }
            #pragma unroll
            for (int r = 0; r < 4; ++r)
                z1s[(nw + lg * 4 + r) * 256 + cb * 16 + cl] = bfu(fmaxf(a[r], 0.f));
        }
        __syncthreads();
        bf16x8 af2[8];
        #pragma unroll
        for (int kc = 0; kc < 8; ++kc)
            af2[kc] = *(const bf16x8*)&z1s[(nw + cl) * 256 + kc * 32 + lg * 8];
        float p0 = 0.f, p1 = 0.f, p2 = 0.f, p3 = 0.f;
        #pragma unroll
        for (int cb = 0; cb < 8; ++cb) {
            float bv = b2s[cb * 16 + cl];
            f32x4 a = {bv, bv, bv, bv};
            #pragma unroll
            for (int kc = 0; kc < 8; ++kc) {
                bf16x8 bf = *(const bf16x8*)&W2s[(((cb << 3) + kc) * 64 + lane) * 8];
                a = __builtin_amdgcn_mfma_f32_16x16x32_bf16(af2[kc], bf, a, 0, 0, 0);
            }
            float w3v = w3s[cb * 16 + cl];
            p0 = fmaf(fmaxf(a[0], 0.f), w3v, p0);
            p1 = fmaf(fmaxf(a[1], 0.f), w3v, p1);
            p2 = fmaf(fmaxf(a[2], 0.f), w3v, p2);
            p3 = fmaf(fmaxf(a[3], 0.f), w3v, p3);
        }
        #pragma unroll
        for (int ofs = 1; ofs <= 8; ofs <<= 1) {
            p0 += __shfl_xor(p0, ofs, 64); p1 += __shfl_xor(p1, ofs, 64);
            p2 += __shfl_xor(p2, ofs, 64); p3 += __shfl_xor(p3, ofs, 64);
        }
        if (cl == 0) {
            int base = n0 + nw + lg * 4;
            if (base + 0 < NND) out[base + 0] = p0 + bb3;
            if (base + 1 < NND) out[base + 1] = p1 + bb3;
            if (base + 2 < NND) out[base + 2] = p2 + bb3;
            if (base + 3 < NND) out[base + 3] = p3 + bb3;
        }
    }
}

extern "C" void kernel_launch(void* const* d_in, const int* in_sizes, int n_in,
                              void* d_out, int out_size, void* d_ws, size_t ws_size,
                              hipStream_t stream) {
    const int*   x_cat   = (const int*)  d_in[0];
    const float* x_num   = (const float*)d_in[1];
    const float* x_coord = (const float*)d_in[2];
    const int*   eidx    = (const int*)  d_in[3];
    const float* emb     = (const float*)d_in[4];
    const float* fB      = (const float*)d_in[5];
    const float* pW      = (const float*)d_in[6];
    const float* pb      = (const float*)d_in[7];
    const float* gatW    = (const float*)d_in[8];
    const float* attS    = (const float*)d_in[9];
    const float* attD    = (const float*)d_in[10];
    const float* gatB    = (const float*)d_in[11];
    const float* bnG     = (const float*)d_in[12];
    const float* bnB     = (const float*)d_in[13];
    const float* W1      = (const float*)d_in[14];
    const float* b1      = (const float*)d_in[15];
    const float* W2      = (const float*)d_in[16];
    const float* b2      = (const float*)d_in[17];
    const float* W3      = (const float*)d_in[18];
    const float* b3      = (const float*)d_in[19];
    float* out = (float*)d_out;

    char* p = (char*)d_ws;
    float* x     = (float*)p;  p += (size_t)NND * HID * 4;
    unsigned short* ybh = (unsigned short*)p; p += (size_t)NND * 256 * 2;
    unsigned short* ybl = (unsigned short*)p; p += (size_t)NND * 256 * 2;
    float* alphS = (float*)p;  p += (size_t)NND * NH * 4;
    float* alphD = (float*)p;  p += (size_t)NND * NH * 4;
    float* accum = (float*)p;  p += (size_t)NND * HID * 4;
    float* bnst  = (float*)p;  p += 1024;
    float* va    = (float*)p;  p += 512 * 4;
    unsigned short* W1f = (unsigned short*)p; p += 16384 * 2;
    unsigned short* W2f = (unsigned short*)p; p += 32768 * 2;
    unsigned short* Wsf = (unsigned short*)p; p += 32768 * 2;
    unsigned short* Wsl = (unsigned short*)p; p += 32768 * 2;
    int*   deg   = (int*)p;    p += (size_t)NND * 4;
    int*   cur   = (int*)p;    p += (size_t)NND * 4;
    int*   off   = (int*)p;    p += (size_t)(NND + 1) * 4 + 4;
    int*   srcs  = (int*)p;    p += (size_t)ETOT * 4;
    int*   bsum  = (int*)p;    p += NB * 4;
    int*   bpre  = (int*)p;    p += NB * 4;

    // CSR build (graph constant across layers) + weight packing
    k_zero_deg<<<NB, 256, 0, stream>>>(deg);
    k_count<<<(ETOT + 255) / 256, 256, 0, stream>>>(eidx, deg);
    k_bsum<<<NB, 256, 0, stream>>>(deg, bsum);
    k_bscan<<<1, 256, 0, stream>>>(bsum, bpre, off);
    k_offsets<<<NB, 256, 0, stream>>>(deg, bpre, off, cur);
    k_fill<<<(ETOT + 255) / 256, 256, 0, stream>>>(eidx, cur, srcs);
    k_packw<<<192, 256, 0, stream>>>(W1, W2, gatW, W1f, W2f, Wsf, Wsl);

    k_feat_proj<<<512, 256, 0, stream>>>(x_cat, x_num, x_coord, emb, fB, pW, pb, x);
    for (int l = 0; l < 2; ++l) {
        k_va<<<1, 512, 0, stream>>>(gatW + (size_t)l * HID * 256,
                                    attS + l * NH * HID, attD + l * NH * HID, va, bnst);
        k_alpha2<<<2048, 256, 0, stream>>>(x, va, alphS, alphD);
        k_aggregate_y<<<2048, 256, 0, stream>>>(off, srcs, alphS, alphD, x, ybh, ybl);
        k_transform_mfma<<<1024, 256, 0, stream>>>(ybh, ybl,
                                                   Wsf + (size_t)l * 16384,
                                                   Wsl + (size_t)l * 16384,
                                                   gatB + l * HID, accum, bnst);
        k_bn_apply<<<3125, 256, 0, stream>>>(accum, bnst, bnG + l * HID, bnB + l * HID, x);
    }
    k_mlp_mfma<<<256, 256, 0, stream>>>(x, W1f, W2f, b1, b2, W3, b3, out);
}

// Round 9
// 368.439 us; speedup vs baseline: 2.3922x; 1.1071x over previous
//
#include <hip/hip_runtime.h>
#include <hip/hip_bf16.h>

#define NND 50000
#define NCATS 3
#define VOC 1000
#define EDIM 16
#define NNUMF 16
#define FMAP 32
#define FIN 128          // 3*16 + 16 + 64
#define HID 64
#define NH 4
#define EB 400000
#define ETOT 450000      // EB + NND self loops
#define M1 256
#define M2 128
#define EPS_BN 1e-5f
#define NB 196           // ceil(NND/256)

typedef __attribute__((ext_vector_type(8))) short bf16x8;
typedef __attribute__((ext_vector_type(4))) float f32x4;

__device__ __forceinline__ float lrelu(float x) { return x > 0.f ? x : 0.2f * x; }

__device__ __forceinline__ unsigned short bfu(float f) {
    unsigned u = __float_as_uint(f);
    unsigned r = (u + 0x7FFFu + ((u >> 16) & 1u)) >> 16;
    return (unsigned short)r;
}
__device__ __forceinline__ float bf2f(unsigned short h) {
    return __uint_as_float((unsigned)h << 16);
}

// ================= CSR build (once; graph identical for both layers) =================
__global__ void k_zero_deg(int* __restrict__ deg) {
    int i = blockIdx.x * blockDim.x + threadIdx.x;
    if (i < NND) deg[i] = 0;
}

__global__ void k_count(const int* __restrict__ ei, int* __restrict__ deg) {
    int e = blockIdx.x * blockDim.x + threadIdx.x;
    if (e >= ETOT) return;
    int d = (e < EB) ? ei[EB + e] : e - EB;
    atomicAdd(&deg[d], 1);
}

__global__ __launch_bounds__(256) void k_bsum(const int* __restrict__ deg,
                                              int* __restrict__ bsum) {
    int i = blockIdx.x * 256 + threadIdx.x;
    int v = (i < NND) ? deg[i] : 0;
    #pragma unroll
    for (int ofs = 32; ofs; ofs >>= 1) v += __shfl_xor(v, ofs, 64);
    __shared__ int ws[4];
    if ((threadIdx.x & 63) == 0) ws[threadIdx.x >> 6] = v;
    __syncthreads();
    if (threadIdx.x == 0) bsum[blockIdx.x] = ws[0] + ws[1] + ws[2] + ws[3];
}

__global__ __launch_bounds__(256) void k_bscan(const int* __restrict__ bsum,
                                               int* __restrict__ bpre,
                                               int* __restrict__ off) {
    __shared__ int sh[256];
    const int t = threadIdx.x;
    int v = (t < NB) ? bsum[t] : 0;
    sh[t] = v;
    __syncthreads();
    for (int ofs = 1; ofs < 256; ofs <<= 1) {
        int u = (t >= ofs) ? sh[t - ofs] : 0;
        __syncthreads();
        sh[t] += u;
        __syncthreads();
    }
    if (t < NB) bpre[t] = sh[t] - v;
    if (t == 0) off[NND] = ETOT;
}

__global__ __launch_bounds__(256) void k_offsets(const int* __restrict__ deg,
                                                 const int* __restrict__ bpre,
                                                 int* __restrict__ off,
                                                 int* __restrict__ cur) {
    __shared__ int sh[256];
    const int t = threadIdx.x;
    const int i = blockIdx.x * 256 + t;
    int v = (i < NND) ? deg[i] : 0;
    sh[t] = v;
    __syncthreads();
    for (int ofs = 1; ofs < 256; ofs <<= 1) {
        int u = (t >= ofs) ? sh[t - ofs] : 0;
        __syncthreads();
        sh[t] += u;
        __syncthreads();
    }
    int excl = sh[t] - v + bpre[blockIdx.x];
    if (i < NND) { off[i] = excl; cur[i] = excl; }
}

__global__ void k_fill(const int* __restrict__ ei, int* __restrict__ cur,
                       int* __restrict__ srcs) {
    int e = blockIdx.x * blockDim.x + threadIdx.x;
    if (e >= ETOT) return;
    int s, d;
    if (e < EB) { s = ei[e]; d = ei[EB + e]; } else { s = d = e - EB; }
    int p = atomicAdd(&cur[d], 1);
    srcs[p] = s;
}

// ===== pack W1/W2 (bf16) and Ws (stacked gatW, both layers, hi+lo split) into MFMA B-frag order =====
__global__ __launch_bounds__(256) void k_packw(
    const float* __restrict__ W1, const float* __restrict__ W2,
    const float* __restrict__ gatW,
    unsigned short* __restrict__ W1f, unsigned short* __restrict__ W2f,
    unsigned short* __restrict__ Wsf, unsigned short* __restrict__ Wsl)
{
    int i = blockIdx.x * 256 + threadIdx.x;
    if (i < 16384) {
        int j = i & 7, l = (i >> 3) & 63, t = i >> 9;
        int kc = t & 1, cb = t >> 1;
        int k = kc * 32 + ((l >> 4) * 8) + j, c = cb * 16 + (l & 15);
        W1f[i] = bfu(W1[k * 256 + c]);
    }
    if (i < 32768) {
        int j = i & 7, l = (i >> 3) & 63, t = i >> 9;
        int kc = t & 7, cb = t >> 3;
        int k = kc * 32 + ((l >> 4) * 8) + j, c = cb * 16 + (l & 15);
        W2f[i] = bfu(W2[k * 128 + c]);
    }
    if (i < 32768) {   // Ws: 2 layers x (4 cb x 8 kc); Ws[r][c] = W[r&63][(r>>6)*64+c]
        int j = i & 7, l = (i >> 3) & 63, t = (i >> 9) & 31, lay = i >> 14;
        int kc = t & 7, cb = t >> 3;
        int r = kc * 32 + ((l >> 4) * 8) + j, c = cb * 16 + (l & 15);
        float w = gatW[lay * 16384 + (r & 63) * 256 + (r >> 6) * 64 + c];
        unsigned short h = bfu(w);
        Wsf[i] = h;
        Wsl[i] = bfu(w - bf2f(h));
    }
}

// ================= K1: featurize + project (128 -> 64), 16-node tiles =================
__global__ __launch_bounds__(256) void k_feat_proj(
    const int* __restrict__ x_cat, const float* __restrict__ x_num,
    const float* __restrict__ x_coord, const float* __restrict__ emb,
    const float* __restrict__ fB, const float* __restrict__ pW,
    const float* __restrict__ pb, float* __restrict__ xout)
{
    __shared__ float Wl[FIN * HID];   // 32 KB
    __shared__ float feat[16][FIN];   // 8 KB
    const int tid = threadIdx.x;
    for (int i = tid; i < FIN * HID; i += 256) Wl[i] = pW[i];
    const int wid = tid >> 6, lane = tid & 63;
    const int col = lane, ng = wid;
    const float bias = pb[col];
    const int ntiles = NND / 16;
    for (int t = blockIdx.x; t < ntiles; t += gridDim.x) {
        const int n0 = t * 16;
        __syncthreads();
        #pragma unroll
        for (int r = 0; r < 4; ++r) {
            const int nn = wid * 4 + r;
            const int n = n0 + nn;
            float v;
            if (lane < 48) {
                int c = lane >> 4, j = lane & 15;
                int idx = x_cat[n * NCATS + c];
                v = emb[((size_t)c * VOC + idx) * EDIM + j];
            } else {
                v = x_num[n * NNUMF + (lane - 48)];
            }
            feat[nn][lane] = v;
            float c0 = x_coord[n * 2 + 0], c1 = x_coord[n * 2 + 1];
            int f = lane & 31;
            float xp = 6.283185307179586f * (c0 * fB[f] + c1 * fB[FMAP + f]);
            feat[nn][64 + lane] = (lane < 32) ? sinf(xp) : cosf(xp);
        }
        __syncthreads();
        float acc[4] = {bias, bias, bias, bias};
        #pragma unroll 4
        for (int k = 0; k < FIN; ++k) {
            float w = Wl[k * HID + col];
            #pragma unroll
            for (int j = 0; j < 4; ++j)
                acc[j] = fmaf(feat[ng + 4 * j][k], w, acc[j]);
        }
        #pragma unroll
        for (int j = 0; j < 4; ++j)
            xout[(size_t)(n0 + ng + 4 * j) * HID + col] = acc[j];
    }
}

// ================= K2a: va = W @ att (64x8) + zero bnst (ALL 256 slots) =================
__global__ __launch_bounds__(512) void k_va(
    const float* __restrict__ W, const float* __restrict__ aS,
    const float* __restrict__ aD, float* __restrict__ va, float* __restrict__ bnst)
{
    const int t = threadIdx.x;
    const int k = t >> 3, q = t & 7, hh = q & 3;
    const float* a = (q >= 4) ? aD : aS;
    float s = 0.f;
    #pragma unroll 8
    for (int d = 0; d < HID; ++d)
        s += W[k * 256 + hh * 64 + d] * a[hh * 64 + d];
    va[k * 8 + q] = s;
    if (t < 256) bnst[t] = 0.f;
}

// ================= K2b: alphas from x =================
__global__ __launch_bounds__(256) void k_alpha2(
    const float* __restrict__ x, const float* __restrict__ va,
    float* __restrict__ alphS, float* __restrict__ alphD)
{
    __shared__ float vas[64 * 8];
    const int tid = threadIdx.x;
    for (int i = tid; i < 512; i += 256) vas[i] = va[i];
    __syncthreads();
    const int lane = tid & 63, wid = tid >> 6;
    const float4 vS = *(const float4*)&vas[lane * 8];
    const float4 vD = *(const float4*)&vas[lane * 8 + 4];
    for (int n = blockIdx.x * 4 + wid; n < NND; n += gridDim.x * 4) {
        float v = x[(size_t)n * HID + lane];
        float s0 = v * vS.x, s1 = v * vS.y, s2 = v * vS.z, s3 = v * vS.w;
        float d0 = v * vD.x, d1 = v * vD.y, d2 = v * vD.z, d3 = v * vD.w;
        #pragma unroll
        for (int ofs = 32; ofs; ofs >>= 1) {
            s0 += __shfl_xor(s0, ofs, 64); s1 += __shfl_xor(s1, ofs, 64);
            s2 += __shfl_xor(s2, ofs, 64); s3 += __shfl_xor(s3, ofs, 64);
            d0 += __shfl_xor(d0, ofs, 64); d1 += __shfl_xor(d1, ofs, 64);
            d2 += __shfl_xor(d2, ofs, 64); d3 += __shfl_xor(d3, ofs, 64);
        }
        if (lane == 0) {
            *(float4*)(alphS + (size_t)n * 4) = make_float4(s0, s1, s2, s3);
            *(float4*)(alphD + (size_t)n * 4) = make_float4(d0, d1, d2, d3);
        }
    }
}

// ====== K3: aggregate x into per-head y — 16-lane groups, 4 dsts/wave ======
__global__ __launch_bounds__(256) void k_aggregate_y(
    const int* __restrict__ off, const int* __restrict__ srcs,
    const float* __restrict__ alphS, const float* __restrict__ alphD,
    const float* __restrict__ x, unsigned short* __restrict__ yh,
    unsigned short* __restrict__ yl)
{
    const int tid = threadIdx.x;
    const int l16 = tid & 15;
    const int gg = blockIdx.x * 16 + (tid >> 4);
    const int ng = gridDim.x * 16;
    for (int d = gg; d < NND; d += ng) {
        const int o0 = off[d];
        const int deg = off[d + 1] - o0;
        const float4 ad = *(const float4*)(alphD + (size_t)d * 4);
        // ---- phase 1: denominators; cache first 16 edges' (src, weights) ----
        float dn0 = 0.f, dn1 = 0.f, dn2 = 0.f, dn3 = 0.f;
        int sE = 0; float w0 = 0.f, w1 = 0.f, w2 = 0.f, w3 = 0.f;
        for (int i = l16; i < deg; i += 16) {
            int s = srcs[o0 + i];
            float4 as = *(const float4*)(alphS + (size_t)s * 4);
            float e0 = __expf(lrelu(as.x + ad.x));
            float e1 = __expf(lrelu(as.y + ad.y));
            float e2 = __expf(lrelu(as.z + ad.z));
            float e3 = __expf(lrelu(as.w + ad.w));
            dn0 += e0; dn1 += e1; dn2 += e2; dn3 += e3;
            if (i < 16) { sE = s; w0 = e0; w1 = e1; w2 = e2; w3 = e3; }
        }
        #pragma unroll
        for (int ofs = 8; ofs; ofs >>= 1) {
            dn0 += __shfl_xor(dn0, ofs, 64); dn1 += __shfl_xor(dn1, ofs, 64);
            dn2 += __shfl_xor(dn2, ofs, 64); dn3 += __shfl_xor(dn3, ofs, 64);
        }
        const float i0 = __fdividef(1.f, dn0 + 1e-16f);
        const float i1 = __fdividef(1.f, dn1 + 1e-16f);
        const float i2 = __fdividef(1.f, dn2 + 1e-16f);
        const float i3 = __fdividef(1.f, dn3 + 1e-16f);
        // ---- phase 2: accumulate; lane = 4 dims (float4) ----
        float ya[4][4];
        #pragma unroll
        for (int h = 0; h < 4; ++h)
            #pragma unroll
            for (int c = 0; c < 4; ++c) ya[h][c] = 0.f;
        for (int c0 = 0; c0 < deg; c0 += 16) {
            const int m = min(16, deg - c0);
            if (c0 > 0) {
                sE = 0; w0 = w1 = w2 = w3 = 0.f;
                if (l16 < m) {
                    sE = srcs[o0 + c0 + l16];
                    float4 as = *(const float4*)(alphS + (size_t)sE * 4);
                    w0 = __expf(lrelu(as.x + ad.x));
                    w1 = __expf(lrelu(as.y + ad.y));
                    w2 = __expf(lrelu(as.z + ad.z));
                    w3 = __expf(lrelu(as.w + ad.w));
                }
            }
            int j = 0;
            for (; j + 2 <= m; j += 2) {
                const int sj0 = __shfl(sE, j + 0, 16);
                const int sj1 = __shfl(sE, j + 1, 16);
                const float4 xv0 = *(const float4*)(x + (size_t)sj0 * HID + l16 * 4);
                const float4 xv1 = *(const float4*)(x + (size_t)sj1 * HID + l16 * 4);
                float a0 = __shfl(w0, j, 16), a1 = __shfl(w1, j, 16);
                float a2 = __shfl(w2, j, 16), a3 = __shfl(w3, j, 16);
                ya[0][0] = fmaf(a0, xv0.x, ya[0][0]); ya[0][1] = fmaf(a0, xv0.y, ya[0][1]);
                ya[0][2] = fmaf(a0, xv0.z, ya[0][2]); ya[0][3] = fmaf(a0, xv0.w, ya[0][3]);
                ya[1][0] = fmaf(a1, xv0.x, ya[1][0]); ya[1][1] = fmaf(a1, xv0.y, ya[1][1]);
                ya[1][2] = fmaf(a1, xv0.z, ya[1][2]); ya[1][3] = fmaf(a1, xv0.w, ya[1][3]);
                ya[2][0] = fmaf(a2, xv0.x, ya[2][0]); ya[2][1] = fmaf(a2, xv0.y, ya[2][1]);
                ya[2][2] = fmaf(a2, xv0.z, ya[2][2]); ya[2][3] = fmaf(a2, xv0.w, ya[2][3]);
                ya[3][0] = fmaf(a3, xv0.x, ya[3][0]); ya[3][1] = fmaf(a3, xv0.y, ya[3][1]);
                ya[3][2] = fmaf(a3, xv0.z, ya[3][2]); ya[3][3] = fmaf(a3, xv0.w, ya[3][3]);
                a0 = __shfl(w0, j + 1, 16); a1 = __shfl(w1, j + 1, 16);
                a2 = __shfl(w2, j + 1, 16); a3 = __shfl(w3, j + 1, 16);
                ya[0][0] = fmaf(a0, xv1.x, ya[0][0]); ya[0][1] = fmaf(a0, xv1.y, ya[0][1]);
                ya[0][2] = fmaf(a0, xv1.z, ya[0][2]); ya[0][3] = fmaf(a0, xv1.w, ya[0][3]);
                ya[1][0] = fmaf(a1, xv1.x, ya[1][0]); ya[1][1] = fmaf(a1, xv1.y, ya[1][1]);
                ya[1][2] = fmaf(a1, xv1.z, ya[1][2]); ya[1][3] = fmaf(a1, xv1.w, ya[1][3]);
                ya[2][0] = fmaf(a2, xv1.x, ya[2][0]); ya[2][1] = fmaf(a2, xv1.y, ya[2][1]);
                ya[2][2] = fmaf(a2, xv1.z, ya[2][2]); ya[2][3] = fmaf(a2, xv1.w, ya[2][3]);
                ya[3][0] = fmaf(a3, xv1.x, ya[3][0]); ya[3][1] = fmaf(a3, xv1.y, ya[3][1]);
                ya[3][2] = fmaf(a3, xv1.z, ya[3][2]); ya[3][3] = fmaf(a3, xv1.w, ya[3][3]);
            }
            if (j < m) {
                const int sj0 = __shfl(sE, j, 16);
                const float4 xv0 = *(const float4*)(x + (size_t)sj0 * HID + l16 * 4);
                float a0 = __shfl(w0, j, 16), a1 = __shfl(w1, j, 16);
                float a2 = __shfl(w2, j, 16), a3 = __shfl(w3, j, 16);
                ya[0][0] = fmaf(a0, xv0.x, ya[0][0]); ya[0][1] = fmaf(a0, xv0.y, ya[0][1]);
                ya[0][2] = fmaf(a0, xv0.z, ya[0][2]); ya[0][3] = fmaf(a0, xv0.w, ya[0][3]);
                ya[1][0] = fmaf(a1, xv0.x, ya[1][0]); ya[1][1] = fmaf(a1, xv0.y, ya[1][1]);
                ya[1][2] = fmaf(a1, xv0.z, ya[1][2]); ya[1][3] = fmaf(a1, xv0.w, ya[1][3]);
                ya[2][0] = fmaf(a2, xv0.x, ya[2][0]); ya[2][1] = fmaf(a2, xv0.y, ya[2][1]);
                ya[2][2] = fmaf(a2, xv0.z, ya[2][2]); ya[2][3] = fmaf(a2, xv0.w, ya[2][3]);
                ya[3][0] = fmaf(a3, xv0.x, ya[3][0]); ya[3][1] = fmaf(a3, xv0.y, ya[3][1]);
                ya[3][2] = fmaf(a3, xv0.z, ya[3][2]); ya[3][3] = fmaf(a3, xv0.w, ya[3][3]);
            }
        }
        // ---- write y (hi/lo bf16), lane covers dims l16*4..+3 per head ----
        const float invh[4] = {i0, i1, i2, i3};
        unsigned short* yhd = yh + (size_t)d * 256 + l16 * 4;
        unsigned short* yld = yl + (size_t)d * 256 + l16 * 4;
        #pragma unroll
        for (int h = 0; h < 4; ++h) {
            ushort4 uh, ul;
            float v0 = ya[h][0] * invh[h]; uh.x = bfu(v0); ul.x = bfu(v0 - bf2f(uh.x));
            float v1 = ya[h][1] * invh[h]; uh.y = bfu(v1); ul.y = bfu(v1 - bf2f(uh.y));
            float v2 = ya[h][2] * invh[h]; uh.z = bfu(v2); ul.z = bfu(v2 - bf2f(uh.z));
            float v3 = ya[h][3] * invh[h]; uh.w = bfu(v3); ul.w = bfu(v3 - bf2f(uh.w));
            *(ushort4*)(yhd + h * 64) = uh;
            *(ushort4*)(yld + h * 64) = ul;
        }
    }
}

// ====== K4: MFMA transform (split bf16): accum = 0.25*(y @ Ws) + b, + BN stats ======
__global__ __launch_bounds__(256) void k_transform_mfma(
    const unsigned short* __restrict__ yh, const unsigned short* __restrict__ yl,
    const unsigned short* __restrict__ Wh, const unsigned short* __restrict__ Wl_,
    const float* __restrict__ gat_b, float* __restrict__ accum,
    float* __restrict__ bnst)
{
    __shared__ float sred[2][4][16];
    const int tid = threadIdx.x;
    const int lane = tid & 63, wid = tid >> 6;   // wid = cb
    const int cl = lane & 15, lg = lane >> 4;
    bf16x8 wfh[8], wfl[8];
    #pragma unroll
    for (int kc = 0; kc < 8; ++kc) {
        wfh[kc] = *(const bf16x8*)&Wh[(size_t)(((wid << 3) + kc) * 64 + lane) * 8];
        wfl[kc] = *(const bf16x8*)&Wl_[(size_t)(((wid << 3) + kc) * 64 + lane) * 8];
    }
    const float bd = gat_b[wid * 16 + cl];
    float s1 = 0.f, s2 = 0.f;
    const int ngrp = NND / 16;   // 3125
    for (int g = blockIdx.x; g < ngrp; g += gridDim.x) {
        const int n0 = g * 16;
        bf16x8 afh[8], afl[8];
        #pragma unroll
        for (int kc = 0; kc < 8; ++kc) {
            afh[kc] = *(const bf16x8*)&yh[(size_t)(n0 + cl) * 256 + kc * 32 + lg * 8];
            afl[kc] = *(const bf16x8*)&yl[(size_t)(n0 + cl) * 256 + kc * 32 + lg * 8];
        }
        f32x4 a = {0.f, 0.f, 0.f, 0.f};
        #pragma unroll
        for (int kc = 0; kc < 8; ++kc)
            a = __builtin_amdgcn_mfma_f32_16x16x32_bf16(afl[kc], wfh[kc], a, 0, 0, 0);
        #pragma unroll
        for (int kc = 0; kc < 8; ++kc)
            a = __builtin_amdgcn_mfma_f32_16x16x32_bf16(afh[kc], wfl[kc], a, 0, 0, 0);
        #pragma unroll
        for (int kc = 0; kc < 8; ++kc)
            a = __builtin_amdgcn_mfma_f32_16x16x32_bf16(afh[kc], wfh[kc], a, 0, 0, 0);
        #pragma unroll
        for (int r = 0; r < 4; ++r) {
            float gv = a[r] * 0.25f + bd;
            accum[(size_t)(n0 + lg * 4 + r) * HID + wid * 16 + cl] = gv;
            s1 += gv; s2 += gv * gv;
        }
    }
    s1 += __shfl_xor(s1, 16, 64); s2 += __shfl_xor(s2, 16, 64);
    s1 += __shfl_xor(s1, 32, 64); s2 += __shfl_xor(s2, 32, 64);
    if (lane < 16) { sred[0][wid][cl] = s1; sred[1][wid][cl] = s2; }
    __syncthreads();
    if (tid < 64) {
        atomicAdd(&bnst[tid], sred[0][tid >> 4][tid & 15]);
        atomicAdd(&bnst[128 + tid], sred[1][tid >> 4][tid & 15]);
    }
}

// ================= K5: BN apply + relu + residual (float4, in place on x) =================
__global__ void k_bn_apply(const float* __restrict__ accum, const float* __restrict__ bnst,
                           const float* __restrict__ gamma, const float* __restrict__ beta,
                           float* __restrict__ x)
{
    int i = blockIdx.x * blockDim.x + threadIdx.x;   // float4 index
    if (i >= NND * 16) return;
    int dg = (i & 15) * 4;
    float4 a = ((const float4*)accum)[i];
    float4 xv = ((float4*)x)[i];
    float r[4]; float av[4] = {a.x, a.y, a.z, a.w}; float xx[4] = {xv.x, xv.y, xv.z, xv.w};
    #pragma unroll
    for (int c = 0; c < 4; ++c) {
        int d = dg + c;
        float mu = bnst[d] * (1.f / NND);
        float var = bnst[128 + d] * (1.f / NND) - mu * mu;
        float inv = rsqrtf(var + EPS_BN);
        float yv = (av[c] - mu) * inv * gamma[d] + beta[d];
        r[c] = fmaxf(yv, 0.f) + xx[c];
    }
    ((float4*)x)[i] = make_float4(r[0], r[1], r[2], r[3]);
}

// ====== K6: fused MFMA MLP ======
__global__ __launch_bounds__(256, 1) void k_mlp_mfma(
    const float* __restrict__ x,
    const unsigned short* __restrict__ W1f, const unsigned short* __restrict__ W2f,
    const float* __restrict__ b1, const float* __restrict__ b2,
    const float* __restrict__ W3, const float* __restrict__ b3,
    float* __restrict__ out)
{
    __shared__ __align__(16) unsigned short W1s[16384];  // 32 KB (frag order)
    __shared__ __align__(16) unsigned short W2s[32768];  // 64 KB (frag order)
    __shared__ __align__(16) unsigned short xs[64 * 64]; // 8 KB
    __shared__ __align__(16) unsigned short z1s[64 * 256]; // 32 KB
    __shared__ float b1s[256], b2s[128], w3s[128];
    const int tid = threadIdx.x;
    const int lane = tid & 63, wid = tid >> 6;
    {
        const uint4* s1 = (const uint4*)W1f; uint4* d1 = (uint4*)W1s;
        for (int i = tid; i < 2048; i += 256) d1[i] = s1[i];
        const uint4* s2 = (const uint4*)W2f; uint4* d2 = (uint4*)W2s;
        for (int i = tid; i < 4096; i += 256) d2[i] = s2[i];
        if (tid < 256) b1s[tid] = b1[tid];
        if (tid < 128) { b2s[tid] = b2[tid]; w3s[tid] = W3[tid]; }
    }
    const float bb3 = b3[0];
    const int nw = wid * 16;
    const int cl = lane & 15, lg = lane >> 4;
    const int ntiles = (NND + 63) / 64;
    for (int t = blockIdx.x; t < ntiles; t += gridDim.x) {
        const int n0 = t * 64;
        __syncthreads();
        #pragma unroll
        for (int q = 0; q < 4; ++q) {
            int i = q * 256 + tid;
            int row = i >> 4, k4 = (i & 15) * 4;
            int n = n0 + row;
            float4 v = (n < NND) ? *(const float4*)(x + (size_t)n * HID + k4)
                                 : make_float4(0.f, 0.f, 0.f, 0.f);
            ushort4 u;
            u.x = bfu(v.x); u.y = bfu(v.y); u.z = bfu(v.z); u.w = bfu(v.w);
            *(ushort4*)&xs[row * 64 + k4] = u;
        }
        __syncthreads();
        #pragma unroll 4
        for (int cb = 0; cb < 16; ++cb) {
            float bv = b1s[cb * 16 + cl];
            f32x4 a = {bv, bv, bv, bv};
            #pragma unroll
            for (int kc = 0; kc < 2; ++kc) {
                bf16x8 af = *(const bf16x8*)&xs[(nw + cl) * 64 + kc * 32 + lg * 8];
                bf16x8 bf = *(const bf16x8*)&W1s[(((cb << 1) + kc) * 64 + lane) * 8];
                a = __builtin_amdgcn_mfma_f32_16x16x32_bf16(af, bf, a, 0, 0, 0);
            }
            #pragma unroll
            for (int r = 0; r < 4; ++r)
                z1s[(nw + lg * 4 + r) * 256 + cb * 16 + cl] = bfu(fmaxf(a[r], 0.f));
        }
        __syncthreads();
        bf16x8 af2[8];
        #pragma unroll
        for (int kc = 0; kc < 8; ++kc)
            af2[kc] = *(const bf16x8*)&z1s[(nw + cl) * 256 + kc * 32 + lg * 8];
        float p0 = 0.f, p1 = 0.f, p2 = 0.f, p3 = 0.f;
        #pragma unroll
        for (int cb = 0; cb < 8; ++cb) {
            float bv = b2s[cb * 16 + cl];
            f32x4 a = {bv, bv, bv, bv};
            #pragma unroll
            for (int kc = 0; kc < 8; ++kc) {
                bf16x8 bf = *(const bf16x8*)&W2s[(((cb << 3) + kc) * 64 + lane) * 8];
                a = __builtin_amdgcn_mfma_f32_16x16x32_bf16(af2[kc], bf, a, 0, 0, 0);
            }
            float w3v = w3s[cb * 16 + cl];
            p0 = fmaf(fmaxf(a[0], 0.f), w3v, p0);
            p1 = fmaf(fmaxf(a[1], 0.f), w3v, p1);
            p2 = fmaf(fmaxf(a[2], 0.f), w3v, p2);
            p3 = fmaf(fmaxf(a[3], 0.f), w3v, p3);
        }
        #pragma unroll
        for (int ofs = 1; ofs <= 8; ofs <<= 1) {
            p0 += __shfl_xor(p0, ofs, 64); p1 += __shfl_xor(p1, ofs, 64);
            p2 += __shfl_xor(p2, ofs, 64); p3 += __shfl_xor(p3, ofs, 64);
        }
        if (cl == 0) {
            int base = n0 + nw + lg * 4;
            if (base + 0 < NND) out[base + 0] = p0 + bb3;
            if (base + 1 < NND) out[base + 1] = p1 + bb3;
            if (base + 2 < NND) out[base + 2] = p2 + bb3;
            if (base + 3 < NND) out[base + 3] = p3 + bb3;
        }
    }
}

extern "C" void kernel_launch(void* const* d_in, const int* in_sizes, int n_in,
                              void* d_out, int out_size, void* d_ws, size_t ws_size,
                              hipStream_t stream) {
    const int*   x_cat   = (const int*)  d_in[0];
    const float* x_num   = (const float*)d_in[1];
    const float* x_coord = (const float*)d_in[2];
    const int*   eidx    = (const int*)  d_in[3];
    const float* emb     = (const float*)d_in[4];
    const float* fB      = (const float*)d_in[5];
    const float* pW      = (const float*)d_in[6];
    const float* pb      = (const float*)d_in[7];
    const float* gatW    = (const float*)d_in[8];
    const float* attS    = (const float*)d_in[9];
    const float* attD    = (const float*)d_in[10];
    const float* gatB    = (const float*)d_in[11];
    const float* bnG     = (const float*)d_in[12];
    const float* bnB     = (const float*)d_in[13];
    const float* W1      = (const float*)d_in[14];
    const float* b1      = (const float*)d_in[15];
    const float* W2      = (const float*)d_in[16];
    const float* b2      = (const float*)d_in[17];
    const float* W3      = (const float*)d_in[18];
    const float* b3      = (const float*)d_in[19];
    float* out = (float*)d_out;

    char* p = (char*)d_ws;
    float* x     = (float*)p;  p += (size_t)NND * HID * 4;
    unsigned short* ybh = (unsigned short*)p; p += (size_t)NND * 256 * 2;
    unsigned short* ybl = (unsigned short*)p; p += (size_t)NND * 256 * 2;
    float* alphS = (float*)p;  p += (size_t)NND * NH * 4;
    float* alphD = (float*)p;  p += (size_t)NND * NH * 4;
    float* accum = (float*)p;  p += (size_t)NND * HID * 4;
    float* bnst  = (float*)p;  p += 1024;
    float* va    = (float*)p;  p += 512 * 4;
    unsigned short* W1f = (unsigned short*)p; p += 16384 * 2;
    unsigned short* W2f = (unsigned short*)p; p += 32768 * 2;
    unsigned short* Wsf = (unsigned short*)p; p += 32768 * 2;
    unsigned short* Wsl = (unsigned short*)p; p += 32768 * 2;
    int*   deg   = (int*)p;    p += (size_t)NND * 4;
    int*   cur   = (int*)p;    p += (size_t)NND * 4;
    int*   off   = (int*)p;    p += (size_t)(NND + 1) * 4 + 4;
    int*   srcs  = (int*)p;    p += (size_t)ETOT * 4;
    int*   bsum  = (int*)p;    p += NB * 4;
    int*   bpre  = (int*)p;    p += NB * 4;

    // CSR build (graph constant across layers) + weight packing
    k_zero_deg<<<NB, 256, 0, stream>>>(deg);
    k_count<<<(ETOT + 255) / 256, 256, 0, stream>>>(eidx, deg);
    k_bsum<<<NB, 256, 0, stream>>>(deg, bsum);
    k_bscan<<<1, 256, 0, stream>>>(bsum, bpre, off);
    k_offsets<<<NB, 256, 0, stream>>>(deg, bpre, off, cur);
    k_fill<<<(ETOT + 255) / 256, 256, 0, stream>>>(eidx, cur, srcs);
    k_packw<<<192, 256, 0, stream>>>(W1, W2, gatW, W1f, W2f, Wsf, Wsl);

    k_feat_proj<<<512, 256, 0, stream>>>(x_cat, x_num, x_coord, emb, fB, pW, pb, x);
    for (int l = 0; l < 2; ++l) {
        k_va<<<1, 512, 0, stream>>>(gatW + (size_t)l * HID * 256,
                                    attS + l * NH * HID, attD + l * NH * HID, va, bnst);
        k_alpha2<<<2048, 256, 0, stream>>>(x, va, alphS, alphD);
        k_aggregate_y<<<3125, 256, 0, stream>>>(off, srcs, alphS, alphD, x, ybh, ybl);
        k_transform_mfma<<<1024, 256, 0, stream>>>(ybh, ybl,
                                                   Wsf + (size_t)l * 16384,
                                                   Wsl + (size_t)l * 16384,
                                                   gatB + l * HID, accum, bnst);
        k_bn_apply<<<3125, 256, 0, stream>>>(accum, bnst, bnG + l * HID, bnB + l * HID, x);
    }
    k_mlp_mfma<<<256, 256, 0, stream>>>(x, W1f, W2f, b1, b2, W3, b3, out);
}

// Round 10
// 342.056 us; speedup vs baseline: 2.5767x; 1.0771x over previous
//
#include <hip/hip_runtime.h>
#include <hip/hip_bf16.h>

#define NND 50000
#define NCATS 3
#define VOC 1000
#define EDIM 16
#define NNUMF 16
#define FMAP 32
#define FIN 128          // 3*16 + 16 + 64
#define HID 64
#define NH 4
#define EB 400000
#define ETOT 450000      // EB + NND self loops
#define M1 256
#define M2 128
#define EPS_BN 1e-5f
#define NB 196           // ceil(NND/256)

typedef __attribute__((ext_vector_type(8))) short bf16x8;
typedef __attribute__((ext_vector_type(4))) float f32x4;

__device__ __forceinline__ float lrelu(float x) { return x > 0.f ? x : 0.2f * x; }

__device__ __forceinline__ unsigned short bfu(float f) {
    unsigned u = __float_as_uint(f);
    unsigned r = (u + 0x7FFFu + ((u >> 16) & 1u)) >> 16;
    return (unsigned short)r;
}
__device__ __forceinline__ float bf2f(unsigned short h) {
    return __uint_as_float((unsigned)h << 16);
}

// ================= CSR build (once; graph identical for both layers) =================
__global__ void k_zero_deg(int* __restrict__ deg) {
    int i = blockIdx.x * blockDim.x + threadIdx.x;
    if (i < NND) deg[i] = 0;
}

__global__ void k_count(const int* __restrict__ ei, int* __restrict__ deg) {
    int e = blockIdx.x * blockDim.x + threadIdx.x;
    if (e >= ETOT) return;
    int d = (e < EB) ? ei[EB + e] : e - EB;
    atomicAdd(&deg[d], 1);
}

__global__ __launch_bounds__(256) void k_bsum(const int* __restrict__ deg,
                                              int* __restrict__ bsum) {
    int i = blockIdx.x * 256 + threadIdx.x;
    int v = (i < NND) ? deg[i] : 0;
    #pragma unroll
    for (int ofs = 32; ofs; ofs >>= 1) v += __shfl_xor(v, ofs, 64);
    __shared__ int ws[4];
    if ((threadIdx.x & 63) == 0) ws[threadIdx.x >> 6] = v;
    __syncthreads();
    if (threadIdx.x == 0) bsum[blockIdx.x] = ws[0] + ws[1] + ws[2] + ws[3];
}

__global__ __launch_bounds__(256) void k_bscan(const int* __restrict__ bsum,
                                               int* __restrict__ bpre,
                                               int* __restrict__ off) {
    __shared__ int sh[256];
    const int t = threadIdx.x;
    int v = (t < NB) ? bsum[t] : 0;
    sh[t] = v;
    __syncthreads();
    for (int ofs = 1; ofs < 256; ofs <<= 1) {
        int u = (t >= ofs) ? sh[t - ofs] : 0;
        __syncthreads();
        sh[t] += u;
        __syncthreads();
    }
    if (t < NB) bpre[t] = sh[t] - v;
    if (t == 0) off[NND] = ETOT;
}

__global__ __launch_bounds__(256) void k_offsets(const int* __restrict__ deg,
                                                 const int* __restrict__ bpre,
                                                 int* __restrict__ off,
                                                 int* __restrict__ cur) {
    __shared__ int sh[256];
    const int t = threadIdx.x;
    const int i = blockIdx.x * 256 + t;
    int v = (i < NND) ? deg[i] : 0;
    sh[t] = v;
    __syncthreads();
    for (int ofs = 1; ofs < 256; ofs <<= 1) {
        int u = (t >= ofs) ? sh[t - ofs] : 0;
        __syncthreads();
        sh[t] += u;
        __syncthreads();
    }
    int excl = sh[t] - v + bpre[blockIdx.x];
    if (i < NND) { off[i] = excl; cur[i] = excl; }
}

__global__ void k_fill(const int* __restrict__ ei, int* __restrict__ cur,
                       int* __restrict__ srcs) {
    int e = blockIdx.x * blockDim.x + threadIdx.x;
    if (e >= ETOT) return;
    int s, d;
    if (e < EB) { s = ei[e]; d = ei[EB + e]; } else { s = d = e - EB; }
    int p = atomicAdd(&cur[d], 1);
    srcs[p] = s;
}

// ===== pack W1/W2 (bf16), Ws (stacked gatW, hi+lo), pW (proj, hi+lo) into MFMA B-frag order =====
__global__ __launch_bounds__(256) void k_packw(
    const float* __restrict__ W1, const float* __restrict__ W2,
    const float* __restrict__ gatW, const float* __restrict__ pW,
    unsigned short* __restrict__ W1f, unsigned short* __restrict__ W2f,
    unsigned short* __restrict__ Wsf, unsigned short* __restrict__ Wsl,
    unsigned short* __restrict__ pWh, unsigned short* __restrict__ pWl)
{
    int i = blockIdx.x * 256 + threadIdx.x;
    if (i < 16384) {
        int j = i & 7, l = (i >> 3) & 63, t = i >> 9;
        int kc = t & 1, cb = t >> 1;
        int k = kc * 32 + ((l >> 4) * 8) + j, c = cb * 16 + (l & 15);
        W1f[i] = bfu(W1[k * 256 + c]);
    }
    if (i < 32768) {
        int j = i & 7, l = (i >> 3) & 63, t = i >> 9;
        int kc = t & 7, cb = t >> 3;
        int k = kc * 32 + ((l >> 4) * 8) + j, c = cb * 16 + (l & 15);
        W2f[i] = bfu(W2[k * 128 + c]);
    }
    if (i < 32768) {   // Ws: 2 layers x (4 cb x 8 kc); Ws[r][c] = W[r&63][(r>>6)*64+c]
        int j = i & 7, l = (i >> 3) & 63, t = (i >> 9) & 31, lay = i >> 14;
        int kc = t & 7, cb = t >> 3;
        int r = kc * 32 + ((l >> 4) * 8) + j, c = cb * 16 + (l & 15);
        float w = gatW[lay * 16384 + (r & 63) * 256 + (r >> 6) * 64 + c];
        unsigned short h = bfu(w);
        Wsf[i] = h;
        Wsl[i] = bfu(w - bf2f(h));
    }
    if (i < 8192) {    // pW: 4 cb x 4 kc; pW[k][c], k<128, c<64
        int j = i & 7, l = (i >> 3) & 63, t = i >> 9;
        int kc = t & 3, cb = t >> 2;
        int k = kc * 32 + ((l >> 4) * 8) + j, c = cb * 16 + (l & 15);
        float w = pW[k * 64 + c];
        unsigned short h = bfu(w);
        pWh[i] = h;
        pWl[i] = bfu(w - bf2f(h));
    }
}

// ====== K1: featurize + MFMA project (128 -> 64), split bf16, 64-node tiles ======
__global__ __launch_bounds__(256) void k_feat_mfma(
    const int* __restrict__ x_cat, const float* __restrict__ x_num,
    const float* __restrict__ x_coord, const float* __restrict__ emb,
    const float* __restrict__ fB,
    const unsigned short* __restrict__ pWh, const unsigned short* __restrict__ pWl,
    const float* __restrict__ pb, float* __restrict__ xout)
{
    __shared__ __align__(16) unsigned short fh[64 * 128];  // 16 KB
    __shared__ __align__(16) unsigned short fl[64 * 128];  // 16 KB
    const int tid = threadIdx.x;
    const int lane = tid & 63, wid = tid >> 6;
    const int cl = lane & 15, lg = lane >> 4;
    const int nw = wid * 16;
    // B fragments in registers (hi/lo)
    bf16x8 wfh[4][4], wfl[4][4];
    #pragma unroll
    for (int cb = 0; cb < 4; ++cb)
        #pragma unroll
        for (int kc = 0; kc < 4; ++kc) {
            wfh[cb][kc] = *(const bf16x8*)&pWh[(((cb << 2) + kc) * 64 + lane) * 8];
            wfl[cb][kc] = *(const bf16x8*)&pWl[(((cb << 2) + kc) * 64 + lane) * 8];
        }
    float pbr[4];
    #pragma unroll
    for (int cb = 0; cb < 4; ++cb) pbr[cb] = pb[cb * 16 + cl];
    const int ntiles = (NND + 63) / 64;   // 782
    for (int t = blockIdx.x; t < ntiles; t += gridDim.x) {
        const int n0 = t * 64;
        __syncthreads();
        // gather + trig -> bf16 hi/lo LDS
        for (int r = 0; r < 16; ++r) {
            const int row = nw + r;
            const int n = n0 + row;
            float v = 0.f, v2 = 0.f;
            if (n < NND) {
                if (lane < 48) {
                    int c = lane >> 4, j = lane & 15;
                    int idx = x_cat[n * NCATS + c];
                    v = emb[((size_t)c * VOC + idx) * EDIM + j];
                } else {
                    v = x_num[n * NNUMF + (lane - 48)];
                }
                float c0 = x_coord[n * 2 + 0], c1 = x_coord[n * 2 + 1];
                int f = lane & 31;
                float xp = 6.283185307179586f * (c0 * fB[f] + c1 * fB[FMAP + f]);
                v2 = (lane < 32) ? sinf(xp) : cosf(xp);
            }
            unsigned short h = bfu(v);
            fh[row * 128 + lane] = h;
            fl[row * 128 + lane] = bfu(v - bf2f(h));
            unsigned short h2 = bfu(v2);
            fh[row * 128 + 64 + lane] = h2;
            fl[row * 128 + 64 + lane] = bfu(v2 - bf2f(h2));
        }
        __syncthreads();
        // A fragments
        bf16x8 afh[4], afl[4];
        #pragma unroll
        for (int kc = 0; kc < 4; ++kc) {
            afh[kc] = *(const bf16x8*)&fh[(nw + cl) * 128 + kc * 32 + lg * 8];
            afl[kc] = *(const bf16x8*)&fl[(nw + cl) * 128 + kc * 32 + lg * 8];
        }
        #pragma unroll
        for (int cb = 0; cb < 4; ++cb) {
            float bv = pbr[cb];
            f32x4 a = {bv, bv, bv, bv};
            #pragma unroll
            for (int kc = 0; kc < 4; ++kc)
                a = __builtin_amdgcn_mfma_f32_16x16x32_bf16(afl[kc], wfh[cb][kc], a, 0, 0, 0);
            #pragma unroll
            for (int kc = 0; kc < 4; ++kc)
                a = __builtin_amdgcn_mfma_f32_16x16x32_bf16(afh[kc], wfl[cb][kc], a, 0, 0, 0);
            #pragma unroll
            for (int kc = 0; kc < 4; ++kc)
                a = __builtin_amdgcn_mfma_f32_16x16x32_bf16(afh[kc], wfh[cb][kc], a, 0, 0, 0);
            #pragma unroll
            for (int r = 0; r < 4; ++r) {
                int n = n0 + nw + lg * 4 + r;
                if (n < NND) xout[(size_t)n * HID + cb * 16 + cl] = a[r];
            }
        }
    }
}

// ====== K2a: va for BOTH layers upfront (depends only on weights) ======
__global__ __launch_bounds__(512) void k_va2(
    const float* __restrict__ gatW, const float* __restrict__ attS,
    const float* __restrict__ attD, float* __restrict__ va2)
{
    const int lay = blockIdx.x;
    const float* W = gatW + (size_t)lay * 16384;
    const int t = threadIdx.x;
    const int k = t >> 3, q = t & 7, hh = q & 3;
    const float* a = ((q >= 4) ? attD : attS) + lay * NH * HID;
    float s = 0.f;
    #pragma unroll 8
    for (int d = 0; d < HID; ++d)
        s += W[k * 256 + hh * 64 + d] * a[hh * 64 + d];
    va2[lay * 512 + k * 8 + q] = s;
}

// ================= K2b: alphas from x (+ zero bnst in block 0) =================
__global__ __launch_bounds__(256) void k_alpha2(
    const float* __restrict__ x, const float* __restrict__ va,
    float* __restrict__ alphS, float* __restrict__ alphD, float* __restrict__ bnst)
{
    __shared__ float vas[64 * 8];
    const int tid = threadIdx.x;
    if (blockIdx.x == 0) bnst[tid] = 0.f;
    for (int i = tid; i < 512; i += 256) vas[i] = va[i];
    __syncthreads();
    const int lane = tid & 63, wid = tid >> 6;
    const float4 vS = *(const float4*)&vas[lane * 8];
    const float4 vD = *(const float4*)&vas[lane * 8 + 4];
    for (int n = blockIdx.x * 4 + wid; n < NND; n += gridDim.x * 4) {
        float v = x[(size_t)n * HID + lane];
        float s0 = v * vS.x, s1 = v * vS.y, s2 = v * vS.z, s3 = v * vS.w;
        float d0 = v * vD.x, d1 = v * vD.y, d2 = v * vD.z, d3 = v * vD.w;
        #pragma unroll
        for (int ofs = 32; ofs; ofs >>= 1) {
            s0 += __shfl_xor(s0, ofs, 64); s1 += __shfl_xor(s1, ofs, 64);
            s2 += __shfl_xor(s2, ofs, 64); s3 += __shfl_xor(s3, ofs, 64);
            d0 += __shfl_xor(d0, ofs, 64); d1 += __shfl_xor(d1, ofs, 64);
            d2 += __shfl_xor(d2, ofs, 64); d3 += __shfl_xor(d3, ofs, 64);
        }
        if (lane == 0) {
            *(float4*)(alphS + (size_t)n * 4) = make_float4(s0, s1, s2, s3);
            *(float4*)(alphD + (size_t)n * 4) = make_float4(d0, d1, d2, d3);
        }
    }
}

// ====== K3: aggregate x into per-head y — 16-lane groups, 4 dsts/wave ======
__global__ __launch_bounds__(256) void k_aggregate_y(
    const int* __restrict__ off, const int* __restrict__ srcs,
    const float* __restrict__ alphS, const float* __restrict__ alphD,
    const float* __restrict__ x, unsigned short* __restrict__ yh,
    unsigned short* __restrict__ yl)
{
    const int tid = threadIdx.x;
    const int l16 = tid & 15;
    const int gg = blockIdx.x * 16 + (tid >> 4);
    const int ng = gridDim.x * 16;
    for (int d = gg; d < NND; d += ng) {
        const int o0 = off[d];
        const int deg = off[d + 1] - o0;
        const float4 ad = *(const float4*)(alphD + (size_t)d * 4);
        float dn0 = 0.f, dn1 = 0.f, dn2 = 0.f, dn3 = 0.f;
        int sE = 0; float w0 = 0.f, w1 = 0.f, w2 = 0.f, w3 = 0.f;
        for (int i = l16; i < deg; i += 16) {
            int s = srcs[o0 + i];
            float4 as = *(const float4*)(alphS + (size_t)s * 4);
            float e0 = __expf(lrelu(as.x + ad.x));
            float e1 = __expf(lrelu(as.y + ad.y));
            float e2 = __expf(lrelu(as.z + ad.z));
            float e3 = __expf(lrelu(as.w + ad.w));
            dn0 += e0; dn1 += e1; dn2 += e2; dn3 += e3;
            if (i < 16) { sE = s; w0 = e0; w1 = e1; w2 = e2; w3 = e3; }
        }
        #pragma unroll
        for (int ofs = 8; ofs; ofs >>= 1) {
            dn0 += __shfl_xor(dn0, ofs, 64); dn1 += __shfl_xor(dn1, ofs, 64);
            dn2 += __shfl_xor(dn2, ofs, 64); dn3 += __shfl_xor(dn3, ofs, 64);
        }
        const float i0 = __fdividef(1.f, dn0 + 1e-16f);
        const float i1 = __fdividef(1.f, dn1 + 1e-16f);
        const float i2 = __fdividef(1.f, dn2 + 1e-16f);
        const float i3 = __fdividef(1.f, dn3 + 1e-16f);
        float ya[4][4];
        #pragma unroll
        for (int h = 0; h < 4; ++h)
            #pragma unroll
            for (int c = 0; c < 4; ++c) ya[h][c] = 0.f;
        for (int c0 = 0; c0 < deg; c0 += 16) {
            const int m = min(16, deg - c0);
            if (c0 > 0) {
                sE = 0; w0 = w1 = w2 = w3 = 0.f;
                if (l16 < m) {
                    sE = srcs[o0 + c0 + l16];
                    float4 as = *(const float4*)(alphS + (size_t)sE * 4);
                    w0 = __expf(lrelu(as.x + ad.x));
                    w1 = __expf(lrelu(as.y + ad.y));
                    w2 = __expf(lrelu(as.z + ad.z));
                    w3 = __expf(lrelu(as.w + ad.w));
                }
            }
            int j = 0;
            for (; j + 2 <= m; j += 2) {
                const int sj0 = __shfl(sE, j + 0, 16);
                const int sj1 = __shfl(sE, j + 1, 16);
                const float4 xv0 = *(const float4*)(x + (size_t)sj0 * HID + l16 * 4);
                const float4 xv1 = *(const float4*)(x + (size_t)sj1 * HID + l16 * 4);
                float a0 = __shfl(w0, j, 16), a1 = __shfl(w1, j, 16);
                float a2 = __shfl(w2, j, 16), a3 = __shfl(w3, j, 16);
                ya[0][0] = fmaf(a0, xv0.x, ya[0][0]); ya[0][1] = fmaf(a0, xv0.y, ya[0][1]);
                ya[0][2] = fmaf(a0, xv0.z, ya[0][2]); ya[0][3] = fmaf(a0, xv0.w, ya[0][3]);
                ya[1][0] = fmaf(a1, xv0.x, ya[1][0]); ya[1][1] = fmaf(a1, xv0.y, ya[1][1]);
                ya[1][2] = fmaf(a1, xv0.z, ya[1][2]); ya[1][3] = fmaf(a1, xv0.w, ya[1][3]);
                ya[2][0] = fmaf(a2, xv0.x, ya[2][0]); ya[2][1] = fmaf(a2, xv0.y, ya[2][1]);
                ya[2][2] = fmaf(a2, xv0.z, ya[2][2]); ya[2][3] = fmaf(a2, xv0.w, ya[2][3]);
                ya[3][0] = fmaf(a3, xv0.x, ya[3][0]); ya[3][1] = fmaf(a3, xv0.y, ya[3][1]);
                ya[3][2] = fmaf(a3, xv0.z, ya[3][2]); ya[3][3] = fmaf(a3, xv0.w, ya[3][3]);
                a0 = __shfl(w0, j + 1, 16); a1 = __shfl(w1, j + 1, 16);
                a2 = __shfl(w2, j + 1, 16); a3 = __shfl(w3, j + 1, 16);
                ya[0][0] = fmaf(a0, xv1.x, ya[0][0]); ya[0][1] = fmaf(a0, xv1.y, ya[0][1]);
                ya[0][2] = fmaf(a0, xv1.z, ya[0][2]); ya[0][3] = fmaf(a0, xv1.w, ya[0][3]);
                ya[1][0] = fmaf(a1, xv1.x, ya[1][0]); ya[1][1] = fmaf(a1, xv1.y, ya[1][1]);
                ya[1][2] = fmaf(a1, xv1.z, ya[1][2]); ya[1][3] = fmaf(a1, xv1.w, ya[1][3]);
                ya[2][0] = fmaf(a2, xv1.x, ya[2][0]); ya[2][1] = fmaf(a2, xv1.y, ya[2][1]);
                ya[2][2] = fmaf(a2, xv1.z, ya[2][2]); ya[2][3] = fmaf(a2, xv1.w, ya[2][3]);
                ya[3][0] = fmaf(a3, xv1.x, ya[3][0]); ya[3][1] = fmaf(a3, xv1.y, ya[3][1]);
                ya[3][2] = fmaf(a3, xv1.z, ya[3][2]); ya[3][3] = fmaf(a3, xv1.w, ya[3][3]);
            }
            if (j < m) {
                const int sj0 = __shfl(sE, j, 16);
                const float4 xv0 = *(const float4*)(x + (size_t)sj0 * HID + l16 * 4);
                float a0 = __shfl(w0, j, 16), a1 = __shfl(w1, j, 16);
                float a2 = __shfl(w2, j, 16), a3 = __shfl(w3, j, 16);
                ya[0][0] = fmaf(a0, xv0.x, ya[0][0]); ya[0][1] = fmaf(a0, xv0.y, ya[0][1]);
                ya[0][2] = fmaf(a0, xv0.z, ya[0][2]); ya[0][3] = fmaf(a0, xv0.w, ya[0][3]);
                ya[1][0] = fmaf(a1, xv0.x, ya[1][0]); ya[1][1] = fmaf(a1, xv0.y, ya[1][1]);
                ya[1][2] = fmaf(a1, xv0.z, ya[1][2]); ya[1][3] = fmaf(a1, xv0.w, ya[1][3]);
                ya[2][0] = fmaf(a2, xv0.x, ya[2][0]); ya[2][1] = fmaf(a2, xv0.y, ya[2][1]);
                ya[2][2] = fmaf(a2, xv0.z, ya[2][2]); ya[2][3] = fmaf(a2, xv0.w, ya[2][3]);
                ya[3][0] = fmaf(a3, xv0.x, ya[3][0]); ya[3][1] = fmaf(a3, xv0.y, ya[3][1]);
                ya[3][2] = fmaf(a3, xv0.z, ya[3][2]); ya[3][3] = fmaf(a3, xv0.w, ya[3][3]);
            }
        }
        const float invh[4] = {i0, i1, i2, i3};
        unsigned short* yhd = yh + (size_t)d * 256 + l16 * 4;
        unsigned short* yld = yl + (size_t)d * 256 + l16 * 4;
        #pragma unroll
        for (int h = 0; h < 4; ++h) {
            ushort4 uh, ul;
            float v0 = ya[h][0] * invh[h]; uh.x = bfu(v0); ul.x = bfu(v0 - bf2f(uh.x));
            float v1 = ya[h][1] * invh[h]; uh.y = bfu(v1); ul.y = bfu(v1 - bf2f(uh.y));
            float v2 = ya[h][2] * invh[h]; uh.z = bfu(v2); ul.z = bfu(v2 - bf2f(uh.z));
            float v3 = ya[h][3] * invh[h]; uh.w = bfu(v3); ul.w = bfu(v3 - bf2f(uh.w));
            *(ushort4*)(yhd + h * 64) = uh;
            *(ushort4*)(yld + h * 64) = ul;
        }
    }
}

// ====== K4: MFMA transform (split bf16): accum = 0.25*(y @ Ws) + b, + BN stats ======
__global__ __launch_bounds__(256) void k_transform_mfma(
    const unsigned short* __restrict__ yh, const unsigned short* __restrict__ yl,
    const unsigned short* __restrict__ Wh, const unsigned short* __restrict__ Wl_,
    const float* __restrict__ gat_b, float* __restrict__ accum,
    float* __restrict__ bnst)
{
    __shared__ float sred[2][4][16];
    const int tid = threadIdx.x;
    const int lane = tid & 63, wid = tid >> 6;   // wid = cb
    const int cl = lane & 15, lg = lane >> 4;
    bf16x8 wfh[8], wfl[8];
    #pragma unroll
    for (int kc = 0; kc < 8; ++kc) {
        wfh[kc] = *(const bf16x8*)&Wh[(size_t)(((wid << 3) + kc) * 64 + lane) * 8];
        wfl[kc] = *(const bf16x8*)&Wl_[(size_t)(((wid << 3) + kc) * 64 + lane) * 8];
    }
    const float bd = gat_b[wid * 16 + cl];
    float s1 = 0.f, s2 = 0.f;
    const int ngrp = NND / 16;   // 3125
    for (int g = blockIdx.x; g < ngrp; g += gridDim.x) {
        const int n0 = g * 16;
        bf16x8 afh[8], afl[8];
        #pragma unroll
        for (int kc = 0; kc < 8; ++kc) {
            afh[kc] = *(const bf16x8*)&yh[(size_t)(n0 + cl) * 256 + kc * 32 + lg * 8];
            afl[kc] = *(const bf16x8*)&yl[(size_t)(n0 + cl) * 256 + kc * 32 + lg * 8];
        }
        f32x4 a = {0.f, 0.f, 0.f, 0.f};
        #pragma unroll
        for (int kc = 0; kc < 8; ++kc)
            a = __builtin_amdgcn_mfma_f32_16x16x32_bf16(afl[kc], wfh[kc], a, 0, 0, 0);
        #pragma unroll
        for (int kc = 0; kc < 8; ++kc)
            a = __builtin_amdgcn_mfma_f32_16x16x32_bf16(afh[kc], wfl[kc], a, 0, 0, 0);
        #pragma unroll
        for (int kc = 0; kc < 8; ++kc)
            a = __builtin_amdgcn_mfma_f32_16x16x32_bf16(afh[kc], wfh[kc], a, 0, 0, 0);
        #pragma unroll
        for (int r = 0; r < 4; ++r) {
            float gv = a[r] * 0.25f + bd;
            accum[(size_t)(n0 + lg * 4 + r) * HID + wid * 16 + cl] = gv;
            s1 += gv; s2 += gv * gv;
        }
    }
    s1 += __shfl_xor(s1, 16, 64); s2 += __shfl_xor(s2, 16, 64);
    s1 += __shfl_xor(s1, 32, 64); s2 += __shfl_xor(s2, 32, 64);
    if (lane < 16) { sred[0][wid][cl] = s1; sred[1][wid][cl] = s2; }
    __syncthreads();
    if (tid < 64) {
        atomicAdd(&bnst[tid], sred[0][tid >> 4][tid & 15]);
        atomicAdd(&bnst[128 + tid], sred[1][tid >> 4][tid & 15]);
    }
}

// ================= K5: BN apply + relu + residual (float4, in place on x) =================
__global__ void k_bn_apply(const float* __restrict__ accum, const float* __restrict__ bnst,
                           const float* __restrict__ gamma, const float* __restrict__ beta,
                           float* __restrict__ x)
{
    int i = blockIdx.x * blockDim.x + threadIdx.x;   // float4 index
    if (i >= NND * 16) return;
    int dg = (i & 15) * 4;
    float4 a = ((const float4*)accum)[i];
    float4 xv = ((float4*)x)[i];
    float r[4]; float av[4] = {a.x, a.y, a.z, a.w}; float xx[4] = {xv.x, xv.y, xv.z, xv.w};
    #pragma unroll
    for (int c = 0; c < 4; ++c) {
        int d = dg + c;
        float mu = bnst[d] * (1.f / NND);
        float var = bnst[128 + d] * (1.f / NND) - mu * mu;
        float inv = rsqrtf(var + EPS_BN);
        float yv = (av[c] - mu) * inv * gamma[d] + beta[d];
        r[c] = fmaxf(yv, 0.f) + xx[c];
    }
    ((float4*)x)[i] = make_float4(r[0], r[1], r[2], r[3]);
}

// ====== K6: fused MFMA MLP ======
__global__ __launch_bounds__(256, 1) void k_mlp_mfma(
    const float* __restrict__ x,
    const unsigned short* __restrict__ W1f, const unsigned short* __restrict__ W2f,
    const float* __restrict__ b1, const float* __restrict__ b2,
    const float* __restrict__ W3, const float* __restrict__ b3,
    float* __restrict__ out)
{
    __shared__ __align__(16) unsigned short W1s[16384];  // 32 KB (frag order)
    __shared__ __align__(16) unsigned short W2s[32768];  // 64 KB (frag order)
    __shared__ __align__(16) unsigned short xs[64 * 64]; // 8 KB
    __shared__ __align__(16) unsigned short z1s[64 * 256]; // 32 KB
    __shared__ float b1s[256], b2s[128], w3s[128];
    const int tid = threadIdx.x;
    const int lane = tid & 63, wid = tid >> 6;
    {
        const uint4* s1 = (const uint4*)W1f; uint4* d1 = (uint4*)W1s;
        for (int i = tid; i < 2048; i += 256) d1[i] = s1[i];
        const uint4* s2 = (const uint4*)W2f; uint4* d2 = (uint4*)W2s;
        for (int i = tid; i < 4096; i += 256) d2[i] = s2[i];
        if (tid < 256) b1s[tid] = b1[tid];
        if (tid < 128) { b2s[tid] = b2[tid]; w3s[tid] = W3[tid]; }
    }
    const float bb3 = b3[0];
    const int nw = wid * 16;
    const int cl = lane & 15, lg = lane >> 4;
    const int ntiles = (NND + 63) / 64;
    for (int t = blockIdx.x; t < ntiles; t += gridDim.x) {
        const int n0 = t * 64;
        __syncthreads();
        #pragma unroll
        for (int q = 0; q < 4; ++q) {
            int i = q * 256 + tid;
            int row = i >> 4, k4 = (i & 15) * 4;
            int n = n0 + row;
            float4 v = (n < NND) ? *(const float4*)(x + (size_t)n * HID + k4)
                                 : make_float4(0.f, 0.f, 0.f, 0.f);
            ushort4 u;
            u.x = bfu(v.x); u.y = bfu(v.y); u.z = bfu(v.z); u.w = bfu(v.w);
            *(ushort4*)&xs[row * 64 + k4] = u;
        }
        __syncthreads();
        #pragma unroll 4
        for (int cb = 0; cb < 16; ++cb) {
            float bv = b1s[cb * 16 + cl];
            f32x4 a = {bv, bv, bv, bv};
            #pragma unroll
            for (int kc = 0; kc < 2; ++kc) {
                bf16x8 af = *(const bf16x8*)&xs[(nw + cl) * 64 + kc * 32 + lg * 8];
                bf16x8 bf = *(const bf16x8*)&W1s[(((cb << 1) + kc) * 64 + lane) * 8];
                a = __builtin_amdgcn_mfma_f32_16x16x32_bf16(af, bf, a, 0, 0, 0);
            }
            #pragma unroll
            for (int r = 0; r < 4; ++r)
                z1s[(nw + lg * 4 + r) * 256 + cb * 16 + cl] = bfu(fmaxf(a[r], 0.f));
        }
        __syncthreads();
        bf16x8 af2[8];
        #pragma unroll
        for (int kc = 0; kc < 8; ++kc)
            af2[kc] = *(const bf16x8*)&z1s[(nw + cl) * 256 + kc * 32 + lg * 8];
        float p0 = 0.f, p1 = 0.f, p2 = 0.f, p3 = 0.f;
        #pragma unroll
        for (int cb = 0; cb < 8; ++cb) {
            float bv = b2s[cb * 16 + cl];
            f32x4 a = {bv, bv, bv, bv};
            #pragma unroll
            for (int kc = 0; kc < 8; ++kc) {
                bf16x8 bf = *(const bf16x8*)&W2s[(((cb << 3) + kc) * 64 + lane) * 8];
                a = __builtin_amdgcn_mfma_f32_16x16x32_bf16(af2[kc], bf, a, 0, 0, 0);
            }
            float w3v = w3s[cb * 16 + cl];
            p0 = fmaf(fmaxf(a[0], 0.f), w3v, p0);
            p1 = fmaf(fmaxf(a[1], 0.f), w3v, p1);
            p2 = fmaf(fmaxf(a[2], 0.f), w3v, p2);
            p3 = fmaf(fmaxf(a[3], 0.f), w3v, p3);
        }
        #pragma unroll
        for (int ofs = 1; ofs <= 8; ofs <<= 1) {
            p0 += __shfl_xor(p0, ofs, 64); p1 += __shfl_xor(p1, ofs, 64);
            p2 += __shfl_xor(p2, ofs, 64); p3 += __shfl_xor(p3, ofs, 64);
        }
        if (cl == 0) {
            int base = n0 + nw + lg * 4;
            if (base + 0 < NND) out[base + 0] = p0 + bb3;
            if (base + 1 < NND) out[base + 1] = p1 + bb3;
            if (base + 2 < NND) out[base + 2] = p2 + bb3;
            if (base + 3 < NND) out[base + 3] = p3 + bb3;
        }
    }
}

extern "C" void kernel_launch(void* const* d_in, const int* in_sizes, int n_in,
                              void* d_out, int out_size, void* d_ws, size_t ws_size,
                              hipStream_t stream) {
    const int*   x_cat   = (const int*)  d_in[0];
    const float* x_num   = (const float*)d_in[1];
    const float* x_coord = (const float*)d_in[2];
    const int*   eidx    = (const int*)  d_in[3];
    const float* emb     = (const float*)d_in[4];
    const float* fB      = (const float*)d_in[5];
    const float* pW      = (const float*)d_in[6];
    const float* pb      = (const float*)d_in[7];
    const float* gatW    = (const float*)d_in[8];
    const float* attS    = (const float*)d_in[9];
    const float* attD    = (const float*)d_in[10];
    const float* gatB    = (const float*)d_in[11];
    const float* bnG     = (const float*)d_in[12];
    const float* bnB     = (const float*)d_in[13];
    const float* W1      = (const float*)d_in[14];
    const float* b1      = (const float*)d_in[15];
    const float* W2      = (const float*)d_in[16];
    const float* b2      = (const float*)d_in[17];
    const float* W3      = (const float*)d_in[18];
    const float* b3      = (const float*)d_in[19];
    float* out = (float*)d_out;

    char* p = (char*)d_ws;
    float* x     = (float*)p;  p += (size_t)NND * HID * 4;
    unsigned short* ybh = (unsigned short*)p; p += (size_t)NND * 256 * 2;
    unsigned short* ybl = (unsigned short*)p; p += (size_t)NND * 256 * 2;
    float* alphS = (float*)p;  p += (size_t)NND * NH * 4;
    float* alphD = (float*)p;  p += (size_t)NND * NH * 4;
    float* accum = (float*)p;  p += (size_t)NND * HID * 4;
    float* bnst  = (float*)p;  p += 1024;
    float* va2   = (float*)p;  p += 1024 * 4;
    unsigned short* W1f = (unsigned short*)p; p += 16384 * 2;
    unsigned short* W2f = (unsigned short*)p; p += 32768 * 2;
    unsigned short* Wsf = (unsigned short*)p; p += 32768 * 2;
    unsigned short* Wsl = (unsigned short*)p; p += 32768 * 2;
    unsigned short* pWh = (unsigned short*)p; p += 8192 * 2;
    unsigned short* pWl = (unsigned short*)p; p += 8192 * 2;
    int*   deg   = (int*)p;    p += (size_t)NND * 4;
    int*   cur   = (int*)p;    p += (size_t)NND * 4;
    int*   off   = (int*)p;    p += (size_t)(NND + 1) * 4 + 4;
    int*   srcs  = (int*)p;    p += (size_t)ETOT * 4;
    int*   bsum  = (int*)p;    p += NB * 4;
    int*   bpre  = (int*)p;    p += NB * 4;

    // CSR build (graph constant across layers) + weight packing + va (both layers)
    k_zero_deg<<<NB, 256, 0, stream>>>(deg);
    k_count<<<(ETOT + 255) / 256, 256, 0, stream>>>(eidx, deg);
    k_bsum<<<NB, 256, 0, stream>>>(deg, bsum);
    k_bscan<<<1, 256, 0, stream>>>(bsum, bpre, off);
    k_offsets<<<NB, 256, 0, stream>>>(deg, bpre, off, cur);
    k_fill<<<(ETOT + 255) / 256, 256, 0, stream>>>(eidx, cur, srcs);
    k_packw<<<192, 256, 0, stream>>>(W1, W2, gatW, pW, W1f, W2f, Wsf, Wsl, pWh, pWl);
    k_va2<<<2, 512, 0, stream>>>(gatW, attS, attD, va2);

    k_feat_mfma<<<512, 256, 0, stream>>>(x_cat, x_num, x_coord, emb, fB, pWh, pWl, pb, x);
    for (int l = 0; l < 2; ++l) {
        k_alpha2<<<2048, 256, 0, stream>>>(x, va2 + (size_t)l * 512, alphS, alphD, bnst);
        k_aggregate_y<<<3125, 256, 0, stream>>>(off, srcs, alphS, alphD, x, ybh, ybl);
        k_transform_mfma<<<1024, 256, 0, stream>>>(ybh, ybl,
                                                   Wsf + (size_t)l * 16384,
                                                   Wsl + (size_t)l * 16384,
                                                   gatB + l * HID, accum, bnst);
        k_bn_apply<<<3125, 256, 0, stream>>>(accum, bnst, bnG + l * HID, bnB + l * HID, x);
    }
    k_mlp_mfma<<<256, 256, 0, stream>>>(x, W1f, W2f, b1, b2, W3, b3, out);
}